// Round 4
// baseline (805.595 us; speedup 1.0000x reference)
//
#include <hip/hip_runtime.h>
#include <cstdint>

// Problem constants
#define Bq   2
#define Tq   2048
#define Dq   2048
#define Hq   16
#define DKq  64
#define DVq  128
#define Cq   64          // chunk len
#define NCq  32          // chunks
#define Mq   4096        // B*T
#define NBH  32          // B*H

typedef __bf16 bf16;
typedef __bf16 bf16x4 __attribute__((ext_vector_type(4)));
typedef __bf16 bf16x8 __attribute__((ext_vector_type(8)));
typedef float  f32x4  __attribute__((ext_vector_type(4)));

__device__ __forceinline__ void gl_lds16(const bf16* g, bf16* l) {
    __builtin_amdgcn_global_load_lds(
        (const __attribute__((address_space(1))) uint32_t*)g,
        (__attribute__((address_space(3))) uint32_t*)l, 16, 0, 0);
}

// ---------------- merged weight transpose+split: all 4 weights in one dispatch ----------------
// blocks 0..2047: Wq -> Qkv rows 0..1023 ; 2048..4095: Wk -> rows 1024..2047 ;
// 4096..8191: Wv -> rows 2048..4095 ; 8192..12287: Wo -> WoT rows 0..2047
__global__ __launch_bounds__(256) void trans_all(const float* __restrict__ Wq,
                                                 const float* __restrict__ Wk,
                                                 const float* __restrict__ Wv,
                                                 const float* __restrict__ Wo,
                                                 bf16* __restrict__ Qhi, bf16* __restrict__ Qlo,
                                                 bf16* __restrict__ WoHi, bf16* __restrict__ WoLo) {
    __shared__ float s[32][33];
    int blk = blockIdx.x;
    const float* W; bf16 *Dh, *Dl; int N, nt, kt; long rowoff;
    if (blk < 2048)      { W = Wq; N = 1024; int t = blk;        nt = t & 31; kt = t >> 5; Dh = Qhi;  Dl = Qlo;  rowoff = 0; }
    else if (blk < 4096) { W = Wk; N = 1024; int t = blk - 2048; nt = t & 31; kt = t >> 5; Dh = Qhi;  Dl = Qlo;  rowoff = 1024; }
    else if (blk < 8192) { W = Wv; N = 2048; int t = blk - 4096; nt = t & 63; kt = t >> 6; Dh = Qhi;  Dl = Qlo;  rowoff = 2048; }
    else                 { W = Wo; N = 2048; int t = blk - 8192; nt = t & 63; kt = t >> 6; Dh = WoHi; Dl = WoLo; rowoff = 0; }
    int tx = threadIdx.x & 31, ty = threadIdx.x >> 5;   // 32 x 8
#pragma unroll
    for (int i = 0; i < 4; i++) {
        int k = kt * 32 + ty + i * 8;
        int n = nt * 32 + tx;
        s[tx][ty + i * 8] = W[(long)k * N + n];
    }
    __syncthreads();
#pragma unroll
    for (int i = 0; i < 4; i++) {
        int n = nt * 32 + ty + i * 8;
        int k = kt * 32 + tx;
        float v = s[ty + i * 8][tx];
        bf16 h = (bf16)v;
        Dh[(rowoff + n) * 2048L + k] = h;
        Dl[(rowoff + n) * 2048L + k] = (bf16)(v - (float)h);
    }
}

// ---------------- fused: hs -> Xhi/Xlo split + rank-16 factors t_gk,t_g ----------------
__global__ __launch_bounds__(256) void hs_prep(const float* __restrict__ X,
                                               const float* __restrict__ Wgk1,
                                               const float* __restrict__ Wg1,
                                               bf16* __restrict__ Xhi, bf16* __restrict__ Xlo,
                                               float* __restrict__ t_gk, float* __restrict__ t_g) {
    __shared__ float sx[2048];
    __shared__ float red[32][9];
    int r = blockIdx.x;
    const float* xr = X + (long)r * Dq;
#pragma unroll
    for (int i = 0; i < 2; i++) {
        int idx = (threadIdx.x + i * 256) * 4;
        float4 v = *(const float4*)(xr + idx);
        *(float4*)&sx[idx] = v;
        bf16x4 h, l;
        h.x = (bf16)v.x; l.x = (bf16)(v.x - (float)h.x);
        h.y = (bf16)v.y; l.y = (bf16)(v.y - (float)h.y);
        h.z = (bf16)v.z; l.z = (bf16)(v.z - (float)h.z);
        h.w = (bf16)v.w; l.w = (bf16)(v.w - (float)h.w);
        *(bf16x4*)(Xhi + (long)r * Dq + idx) = h;
        *(bf16x4*)(Xlo + (long)r * Dq + idx) = l;
    }
    __syncthreads();
    int out = threadIdx.x & 31, part = threadIdx.x >> 5;
    int col = out & 15;
    const float* W = (out < 16) ? Wgk1 : Wg1;
    float s = 0.f;
    for (int kk = part; kk < Dq; kk += 8)
        s += sx[kk] * W[kk * 16 + col];
    red[out][part] = s;
    __syncthreads();
    if (threadIdx.x < 32) {
        float t = 0.f;
#pragma unroll
        for (int p = 0; p < 8; p++) t += red[threadIdx.x][p];
        int c = threadIdx.x & 15;
        if (threadIdx.x < 16) t_gk[r * 16 + c] = t;
        else                  t_g [r * 16 + c] = t;
    }
}

// ---------------- split-3 GEMM, 4-buffer single K-loop ----------------
// acc = AhiBhi + AloBhi + AhiBlo (48 MFMA per barrier).
// mode 0: plain write to o0 [M][Ncols]; mode 1: qkv routing with silu (+0.125 for q cols)
__global__ __launch_bounds__(256, 2) void gemm3(const bf16* __restrict__ Ahi,
                                                const bf16* __restrict__ Alo,
                                                const bf16* __restrict__ Bhi,
                                                const bf16* __restrict__ Blo,
                                                float* __restrict__ o0,
                                                float* __restrict__ o1,
                                                float* __restrict__ o2,
                                                int Ncols, int mode) {
    const int K = 2048;
    __shared__ __align__(16) bf16 sAh[128 * 32];
    __shared__ __align__(16) bf16 sAl[128 * 32];
    __shared__ __align__(16) bf16 sBh[128 * 32];
    __shared__ __align__(16) bf16 sBl[128 * 32];
    int tid = threadIdx.x;
    int wave = tid >> 6, lane = tid & 63;
    int quad = lane >> 4, l16 = lane & 15;
    int bm = blockIdx.x & 31;
    int bn = blockIdx.x >> 5;
    int wm = (wave >> 1) * 64, wn = (wave & 1) * 64;

    const int c0 = tid, c1 = tid + 256;
    const int ar0 = c0 >> 2, ak0 = (c0 & 3) * 8;
    const int ar1 = c1 >> 2, ak1 = (c1 & 3) * 8;
    const bf16* Ah = Ahi + (long)(bm * 128) * K;
    const bf16* Al = Alo + (long)(bm * 128) * K;
    const bf16* Bh = Bhi + (long)(bn * 128) * K;
    const bf16* Bl = Blo + (long)(bn * 128) * K;

    f32x4 acc[4][4] = {};

    for (int k0 = 0; k0 < K; k0 += 32) {
        gl_lds16(Ah + (long)ar0 * K + k0 + ak0, sAh + c0 * 8);
        gl_lds16(Ah + (long)ar1 * K + k0 + ak1, sAh + c1 * 8);
        gl_lds16(Al + (long)ar0 * K + k0 + ak0, sAl + c0 * 8);
        gl_lds16(Al + (long)ar1 * K + k0 + ak1, sAl + c1 * 8);
        gl_lds16(Bh + (long)ar0 * K + k0 + ak0, sBh + c0 * 8);
        gl_lds16(Bh + (long)ar1 * K + k0 + ak1, sBh + c1 * 8);
        gl_lds16(Bl + (long)ar0 * K + k0 + ak0, sBl + c0 * 8);
        gl_lds16(Bl + (long)ar1 * K + k0 + ak1, sBl + c1 * 8);
        __syncthreads();
        bf16x8 ah[4], bh[4], xf[4];
#pragma unroll
        for (int i = 0; i < 4; i++)
            ah[i] = *(const bf16x8*)(sAh + (wm + i * 16 + l16) * 32 + quad * 8);
#pragma unroll
        for (int j = 0; j < 4; j++)
            bh[j] = *(const bf16x8*)(sBh + (wn + j * 16 + l16) * 32 + quad * 8);
#pragma unroll
        for (int i = 0; i < 4; i++)
#pragma unroll
            for (int j = 0; j < 4; j++)
                acc[i][j] = __builtin_amdgcn_mfma_f32_16x16x32_bf16(ah[i], bh[j], acc[i][j], 0, 0, 0);
#pragma unroll
        for (int i = 0; i < 4; i++)
            xf[i] = *(const bf16x8*)(sAl + (wm + i * 16 + l16) * 32 + quad * 8);
#pragma unroll
        for (int i = 0; i < 4; i++)
#pragma unroll
            for (int j = 0; j < 4; j++)
                acc[i][j] = __builtin_amdgcn_mfma_f32_16x16x32_bf16(xf[i], bh[j], acc[i][j], 0, 0, 0);
#pragma unroll
        for (int j = 0; j < 4; j++)
            xf[j] = *(const bf16x8*)(sBl + (wn + j * 16 + l16) * 32 + quad * 8);
#pragma unroll
        for (int i = 0; i < 4; i++)
#pragma unroll
            for (int j = 0; j < 4; j++)
                acc[i][j] = __builtin_amdgcn_mfma_f32_16x16x32_bf16(ah[i], xf[j], acc[i][j], 0, 0, 0);
        __syncthreads();
    }
#pragma unroll
    for (int i = 0; i < 4; i++)
#pragma unroll
        for (int j = 0; j < 4; j++) {
            int row0 = bm * 128 + wm + i * 16 + quad * 4;
            int col  = bn * 128 + wn + j * 16 + l16;
            if (mode == 0) {
#pragma unroll
                for (int r = 0; r < 4; r++)
                    o0[(long)(row0 + r) * Ncols + col] = acc[i][j][r];
            } else {
                float scale = (col < 1024) ? 0.125f : 1.0f;
                float* dst; int cw, cc;
                if (col < 1024)      { dst = o0; cw = 1024; cc = col; }
                else if (col < 2048) { dst = o1; cw = 1024; cc = col - 1024; }
                else                 { dst = o2; cw = 2048; cc = col - 2048; }
#pragma unroll
                for (int r = 0; r < 4; r++) {
                    float x = acc[i][j][r];
                    x = x / (1.f + __expf(-x)) * scale;
                    dst[(long)(row0 + r) * cw + cc] = x;
                }
            }
        }
}

// ---------------- GLA pass 1: per-chunk U, decay (gk computed inline) ----------------
#define ST 76
__global__ __launch_bounds__(256) void gla_pass1(const float* __restrict__ kbuf,
                                                 const float* __restrict__ vbuf,
                                                 const float* __restrict__ t_gk,
                                                 const float* __restrict__ Wgk2,
                                                 const float* __restrict__ bgk2,
                                                 float* __restrict__ U,
                                                 float* __restrict__ dec) {
    __shared__ float sG[64 * ST];
    __shared__ float sK[64 * ST];
    // overlay gk tables on sK (sK not written until after they're consumed)
    float* sTg = sK;            // 64*16
    float* sWg = sK + 1024;     // 16*64
    float* sb  = sK + 2048;     // 64
    int blk = blockIdx.x;                       // (b*16+h)*32 + c
    int c = blk & 31, h = (blk >> 5) & 15, b = blk >> 9;
    int tid = threadIdx.x;
    long rowbase = (long)b * Tq + c * 64;
    {
        int idx = tid * 4;
        *(float4*)&sTg[idx] = *(const float4*)(t_gk + rowbase * 16 + idx);
        int rr = idx >> 6, dd = idx & 63;
        *(float4*)&sWg[idx] = *(const float4*)(Wgk2 + rr * 1024 + h * 64 + dd);
    }
    if (tid < 64) sb[tid] = bgk2[h * 64 + tid];
    __syncthreads();
    // gk (pre-cumsum) into sG
#pragma unroll
    for (int i = 0; i < 16; i++) {
        int idx = tid + i * 256;
        int t = idx >> 6, d = idx & 63;
        float z = sb[d];
#pragma unroll
        for (int rr = 0; rr < 16; rr++) z += sTg[t * 16 + rr] * sWg[rr * 64 + d];
        float ls = fminf(z, 0.f) - log1pf(__expf(-fabsf(z)));
        sG[t * ST + d] = ls * 0.0625f;
    }
    __syncthreads();
    if (tid < 64) {
        float run = 0.f;
        for (int t = 0; t < 64; t++) { run += sG[t * ST + tid]; sG[t * ST + tid] = run; }
        dec[blk * 64 + tid] = __expf(run);
    }
    __syncthreads();
#pragma unroll
    for (int i = 0; i < 16; i++) {
        int idx = tid + i * 256;
        int t = idx >> 6, d = idx & 63;
        float gl = sG[63 * ST + d];
        sK[t * ST + d] = kbuf[(rowbase + t) * 1024 + h * 64 + d] * __expf(gl - sG[t * ST + d]);
    }
    __syncthreads();
    int ty = tid >> 4, tx = tid & 15;
    float acc[4][8] = {};
    const float* vb = vbuf + rowbase * 2048 + h * 128 + tx * 8;
    for (int t = 0; t < 64; t++) {
        float4 v0 = *(const float4*)(vb + (long)t * 2048);
        float4 v1 = *(const float4*)(vb + (long)t * 2048 + 4);
        float ve[8] = {v0.x, v0.y, v0.z, v0.w, v1.x, v1.y, v1.z, v1.w};
#pragma unroll
        for (int r = 0; r < 4; r++) {
            float kd = sK[t * ST + ty * 4 + r];
#pragma unroll
            for (int e = 0; e < 8; e++) acc[r][e] += kd * ve[e];
        }
    }
    float* Ub = U + (long)blk * 8192 + (ty * 4) * 128 + tx * 8;
#pragma unroll
    for (int r = 0; r < 4; r++) {
        float4 o0 = {acc[r][0], acc[r][1], acc[r][2], acc[r][3]};
        float4 o1 = {acc[r][4], acc[r][5], acc[r][6], acc[r][7]};
        *(float4*)(Ub + r * 128)     = o0;
        *(float4*)(Ub + r * 128 + 4) = o1;
    }
}

// ---------------- GLA pass 2: scan over chunks (in-place U -> S_prev) ----------------
__global__ __launch_bounds__(256) void gla_pass2(float* __restrict__ U,
                                                 const float* __restrict__ dec) {
    int bh = blockIdx.x >> 5;
    int base = (blockIdx.x & 31) * 256 + threadIdx.x;   // 0..8191
    int d = base >> 7;
    float S = 0.f;
    long off = (long)bh * NCq * 8192 + base;
    for (int c = 0; c < NCq; c++) {
        float u = U[off + (long)c * 8192];
        float dc = dec[(bh * NCq + c) * 64 + d];
        U[off + (long)c * 8192] = S;       // state BEFORE chunk c
        S = S * dc + u;
    }
}

// ---------------- GLA pass 3: o = qg@S_prev + tril(qg kg^T)@v, fused RMS-norm+gate -> bf16 hi/lo --------
__global__ __launch_bounds__(256) void gla_pass3(const float* __restrict__ qbuf,
                                                 const float* __restrict__ kbuf,
                                                 const float* __restrict__ vbuf,
                                                 const float* __restrict__ t_gk,
                                                 const float* __restrict__ Wgk2,
                                                 const float* __restrict__ bgk2,
                                                 const float* __restrict__ t_g,
                                                 const float* __restrict__ Wg2,
                                                 const float* __restrict__ bg2,
                                                 const float* __restrict__ gnw,
                                                 const float* __restrict__ Sbuf,
                                                 bf16* __restrict__ Ohi,
                                                 bf16* __restrict__ Olo) {
    __shared__ float sQ[64 * ST];
    __shared__ float sK[64 * ST];
    __shared__ float sA[64 * ST];   // G, then A
    int blk = blockIdx.x;
    int c = blk & 31, h = (blk >> 5) & 15, b = blk >> 9;
    int tid = threadIdx.x;
    long rowbase = (long)b * Tq + c * 64;
    // phase 0: gk tables overlaid on sQ (sQ written later, after they're consumed)
    {
        float* sTgk = sQ;          // 64*16
        float* sWgk = sQ + 1024;   // 16*64
        float* sbk  = sQ + 2048;   // 64
        int idx = tid * 4;
        *(float4*)&sTgk[idx] = *(const float4*)(t_gk + rowbase * 16 + idx);
        int rr = idx >> 6, dd = idx & 63;
        *(float4*)&sWgk[idx] = *(const float4*)(Wgk2 + rr * 1024 + h * 64 + dd);
        if (tid < 64) sbk[tid] = bgk2[h * 64 + tid];
        __syncthreads();
#pragma unroll
        for (int i = 0; i < 16; i++) {
            int idx2 = tid + i * 256;
            int t = idx2 >> 6, d = idx2 & 63;
            float z = sbk[d];
#pragma unroll
            for (int rr2 = 0; rr2 < 16; rr2++) z += sTgk[t * 16 + rr2] * sWgk[rr2 * 64 + d];
            float ls = fminf(z, 0.f) - log1pf(__expf(-fabsf(z)));
            sA[t * ST + d] = ls * 0.0625f;
        }
    }
    __syncthreads();
    if (tid < 64) {
        float run = 0.f;
        for (int t = 0; t < 64; t++) { run += sA[t * ST + tid]; sA[t * ST + tid] = run; }
    }
    __syncthreads();
#pragma unroll
    for (int i = 0; i < 16; i++) {
        int idx = tid + i * 256;
        int t = idx >> 6, d = idx & 63;
        float G = sA[t * ST + d];
        long g = (rowbase + t) * 1024 + h * 64 + d;
        sQ[t * ST + d] = qbuf[g] * __expf(G);
        sK[t * ST + d] = kbuf[g] * __expf(-G);
    }
    __syncthreads();
    int ty = tid >> 4, tx = tid & 15;
    // A = tril(sQ sK^T)
    {
        float a[4][4] = {};
        for (int d4 = 0; d4 < 16; d4++) {
            float4 qv[4], kv[4];
#pragma unroll
            for (int r = 0; r < 4; r++) qv[r] = *(const float4*)&sQ[(ty * 4 + r) * ST + d4 * 4];
#pragma unroll
            for (int cc = 0; cc < 4; cc++) kv[cc] = *(const float4*)&sK[(tx * 4 + cc) * ST + d4 * 4];
#pragma unroll
            for (int r = 0; r < 4; r++)
#pragma unroll
                for (int cc = 0; cc < 4; cc++)
                    a[r][cc] += qv[r].x * kv[cc].x + qv[r].y * kv[cc].y +
                                qv[r].z * kv[cc].z + qv[r].w * kv[cc].w;
        }
#pragma unroll
        for (int r = 0; r < 4; r++) {
            int ii = ty * 4 + r;
            float4 row;
            row.x = (tx * 4 + 0 <= ii) ? a[r][0] : 0.f;
            row.y = (tx * 4 + 1 <= ii) ? a[r][1] : 0.f;
            row.z = (tx * 4 + 2 <= ii) ? a[r][2] : 0.f;
            row.w = (tx * 4 + 3 <= ii) ? a[r][3] : 0.f;
            *(float4*)&sA[ii * ST + tx * 4] = row;
        }
    }
    __syncthreads();
    // stage gate tables into sK region (sK's last read was the A-compute, fenced by the barrier above)
    float* sWg2v = sK;          // 16*128
    float* sTgv  = sK + 2048;   // 64*16
    float* sbg   = sK + 3072;   // 128
    {
#pragma unroll
        for (int i = 0; i < 2; i++) {
            int idx = tid * 4 + i * 1024;
            int rr = idx >> 7, ee = idx & 127;
            *(float4*)&sWg2v[idx] = *(const float4*)(Wg2 + (long)rr * 2048 + h * 128 + ee);
        }
        int idx = tid * 4;
        *(float4*)&sTgv[idx] = *(const float4*)(t_g + rowbase * 16 + idx);
        if (tid < 128) sbg[tid] = bg2[h * 128 + tid];
    }
    // o accumulation: rows ty*4..+3, cols tx*8..+7 (reads sQ, sA, global — not sK)
    float acc[4][8] = {};
    const float* Sb = Sbuf + (long)blk * 8192 + tx * 8;
    for (int d = 0; d < 64; d++) {
        float4 s0 = *(const float4*)(Sb + d * 128);
        float4 s1 = *(const float4*)(Sb + d * 128 + 4);
        float se[8] = {s0.x, s0.y, s0.z, s0.w, s1.x, s1.y, s1.z, s1.w};
#pragma unroll
        for (int r = 0; r < 4; r++) {
            float qv = sQ[(ty * 4 + r) * ST + d];
#pragma unroll
            for (int e = 0; e < 8; e++) acc[r][e] += qv * se[e];
        }
    }
    const float* vb = vbuf + rowbase * 2048 + h * 128 + tx * 8;
    for (int j = 0; j < ty * 4 + 4; j++) {
        float4 v0 = *(const float4*)(vb + (long)j * 2048);
        float4 v1 = *(const float4*)(vb + (long)j * 2048 + 4);
        float ve[8] = {v0.x, v0.y, v0.z, v0.w, v1.x, v1.y, v1.z, v1.w};
#pragma unroll
        for (int r = 0; r < 4; r++) {
            float av = sA[(ty * 4 + r) * ST + j];
#pragma unroll
            for (int e = 0; e < 8; e++) acc[r][e] += av * ve[e];
        }
    }
    __syncthreads();   // gate tables visible
    // fused epilogue: RMS-norm over DV(=128, the row this thread-group holds), * gnw, * sigmoid(g)
#pragma unroll
    for (int r = 0; r < 4; r++) {
        int ii = ty * 4 + r;
        float ss = 0.f;
#pragma unroll
        for (int e = 0; e < 8; e++) ss += acc[r][e] * acc[r][e];
        ss += __shfl_xor(ss, 1);
        ss += __shfl_xor(ss, 2);
        ss += __shfl_xor(ss, 4);
        ss += __shfl_xor(ss, 8);      // sum over the 16 tx lanes (same ty)
        float scale = rsqrtf(ss * (1.f / 128.f) + 1e-5f);
        bf16x8 hv, lv;
#pragma unroll
        for (int e = 0; e < 8; e++) {
            int col = tx * 8 + e;
            float g = sbg[col];
#pragma unroll
            for (int rr = 0; rr < 16; rr++) g += sTgv[ii * 16 + rr] * sWg2v[rr * 128 + col];
            float y = acc[r][e] * scale * gnw[col] / (1.f + __expf(-g));
            bf16 hh = (bf16)y;
            hv[e] = hh;
            lv[e] = (bf16)(y - (float)hh);
        }
        long off = (rowbase + ii) * 2048 + h * 128 + tx * 8;
        *(bf16x8*)(Ohi + off) = hv;
        *(bf16x8*)(Olo + off) = lv;
    }
}

extern "C" void kernel_launch(void* const* d_in, const int* in_sizes, int n_in,
                              void* d_out, int out_size, void* d_ws, size_t ws_size,
                              hipStream_t stream) {
    const float* hs   = (const float*)d_in[0];
    const float* Wq   = (const float*)d_in[1];
    const float* Wk   = (const float*)d_in[2];
    const float* Wv   = (const float*)d_in[3];
    const float* Wgk1 = (const float*)d_in[4];
    const float* Wgk2 = (const float*)d_in[5];
    const float* bgk2 = (const float*)d_in[6];
    const float* Wg1  = (const float*)d_in[7];
    const float* Wg2  = (const float*)d_in[8];
    const float* bg2  = (const float*)d_in[9];
    const float* Wo   = (const float*)d_in[10];
    const float* gnw  = (const float*)d_in[11];

    char* w = (char*)d_ws;
    auto alloc = [&](size_t bytes) {
        char* p = w; w += (bytes + 255) & ~size_t(255); return (void*)p;
    };
    bf16*  Xhi    = (bf16*) alloc((size_t)Mq * Dq * 2);        // 16 MB (reused for Ohi)
    bf16*  Xlo    = (bf16*) alloc((size_t)Mq * Dq * 2);        // 16 MB (reused for Olo)
    bf16*  WqkvThi= (bf16*) alloc((size_t)4096 * 2048 * 2);    // 16 MB  [q|k|v] rows
    bf16*  WqkvTlo= (bf16*) alloc((size_t)4096 * 2048 * 2);    // 16 MB
    bf16*  WoThi  = (bf16*) alloc((size_t)2048 * 2048 * 2);    // 8 MB
    bf16*  WoTlo  = (bf16*) alloc((size_t)2048 * 2048 * 2);    // 8 MB
    float* qb     = (float*)alloc((size_t)Mq * 1024 * 4);      // 16 MB
    float* kb     = (float*)alloc((size_t)Mq * 1024 * 4);      // 16 MB
    float* vb     = (float*)alloc((size_t)Mq * 2048 * 4);      // 32 MB
    float* t_gk   = (float*)alloc((size_t)Mq * 16 * 4);
    float* t_g    = (float*)alloc((size_t)Mq * 16 * 4);
    float* U      = (float*)alloc((size_t)NBH * NCq * 8192 * 4); // 33.5 MB (Sbuf in-place)
    float* dec    = (float*)alloc((size_t)NBH * NCq * 64 * 4);

    trans_all<<<12288, 256, 0, stream>>>(Wq, Wk, Wv, Wo, WqkvThi, WqkvTlo, WoThi, WoTlo);
    hs_prep<<<Mq, 256, 0, stream>>>(hs, Wgk1, Wg1, Xhi, Xlo, t_gk, t_g);

    // fused q|k|v GEMM: N = 4096, 32x32 = 1024 blocks
    gemm3<<<32 * 32, 256, 0, stream>>>(Xhi, Xlo, WqkvThi, WqkvTlo, qb, kb, vb, 4096, 1);

    gla_pass1<<<NBH * NCq, 256, 0, stream>>>(kb, vb, t_gk, Wgk2, bgk2, U, dec);
    gla_pass2<<<NBH * NCq, 256, 0, stream>>>(U, dec);
    // pass3 writes normalized+gated output directly as bf16 hi/lo into Xhi/Xlo (X dead after qkv GEMM)
    gla_pass3<<<NBH * NCq, 256, 0, stream>>>(qb, kb, vb, t_gk, Wgk2, bgk2,
                                             t_g, Wg2, bg2, gnw, U, Xhi, Xlo);

    // out GEMM: N = 2048, 32x16 = 512 blocks
    gemm3<<<32 * 16, 256, 0, stream>>>(Xhi, Xlo, WoThi, WoTlo, (float*)d_out, nullptr, nullptr, 2048, 0);
}

// Round 5
// 772.483 us; speedup vs baseline: 1.0429x; 1.0429x over previous
//
#include <hip/hip_runtime.h>
#include <cstdint>

// Problem constants
#define Bq   2
#define Tq   2048
#define Dq   2048
#define Hq   16
#define DKq  64
#define DVq  128
#define Cq   64          // chunk len
#define NCq  32          // chunks
#define Mq   4096        // B*T
#define NBH  32          // B*H

typedef __bf16 bf16;
typedef __bf16 bf16x4 __attribute__((ext_vector_type(4)));
typedef __bf16 bf16x8 __attribute__((ext_vector_type(8)));
typedef float  f32x4  __attribute__((ext_vector_type(4)));

__device__ __forceinline__ void gl_lds16(const bf16* g, bf16* l) {
    __builtin_amdgcn_global_load_lds(
        (const __attribute__((address_space(1))) uint32_t*)g,
        (__attribute__((address_space(3))) uint32_t*)l, 16, 0, 0);
}

// ---------------- merged weight transpose+split: all 4 weights in one dispatch ----------------
__global__ __launch_bounds__(256) void trans_all(const float* __restrict__ Wq,
                                                 const float* __restrict__ Wk,
                                                 const float* __restrict__ Wv,
                                                 const float* __restrict__ Wo,
                                                 bf16* __restrict__ Qhi, bf16* __restrict__ Qlo,
                                                 bf16* __restrict__ WoHi, bf16* __restrict__ WoLo) {
    __shared__ float s[32][33];
    int blk = blockIdx.x;
    const float* W; bf16 *Dh, *Dl; int N, nt, kt; long rowoff;
    if (blk < 2048)      { W = Wq; N = 1024; int t = blk;        nt = t & 31; kt = t >> 5; Dh = Qhi;  Dl = Qlo;  rowoff = 0; }
    else if (blk < 4096) { W = Wk; N = 1024; int t = blk - 2048; nt = t & 31; kt = t >> 5; Dh = Qhi;  Dl = Qlo;  rowoff = 1024; }
    else if (blk < 8192) { W = Wv; N = 2048; int t = blk - 4096; nt = t & 63; kt = t >> 6; Dh = Qhi;  Dl = Qlo;  rowoff = 2048; }
    else                 { W = Wo; N = 2048; int t = blk - 8192; nt = t & 63; kt = t >> 6; Dh = WoHi; Dl = WoLo; rowoff = 0; }
    int tx = threadIdx.x & 31, ty = threadIdx.x >> 5;   // 32 x 8
#pragma unroll
    for (int i = 0; i < 4; i++) {
        int k = kt * 32 + ty + i * 8;
        int n = nt * 32 + tx;
        s[tx][ty + i * 8] = W[(long)k * N + n];
    }
    __syncthreads();
#pragma unroll
    for (int i = 0; i < 4; i++) {
        int n = nt * 32 + ty + i * 8;
        int k = kt * 32 + tx;
        float v = s[ty + i * 8][tx];
        bf16 h = (bf16)v;
        Dh[(rowoff + n) * 2048L + k] = h;
        Dl[(rowoff + n) * 2048L + k] = (bf16)(v - (float)h);
    }
}

// ---------------- fused: hs -> Xhi/Xlo split + rank-16 factors t_gk,t_g ----------------
__global__ __launch_bounds__(256) void hs_prep(const float* __restrict__ X,
                                               const float* __restrict__ Wgk1,
                                               const float* __restrict__ Wg1,
                                               bf16* __restrict__ Xhi, bf16* __restrict__ Xlo,
                                               float* __restrict__ t_gk, float* __restrict__ t_g) {
    __shared__ float sx[2048];
    __shared__ float red[32][9];
    int r = blockIdx.x;
    const float* xr = X + (long)r * Dq;
#pragma unroll
    for (int i = 0; i < 2; i++) {
        int idx = (threadIdx.x + i * 256) * 4;
        float4 v = *(const float4*)(xr + idx);
        *(float4*)&sx[idx] = v;
        bf16x4 h, l;
        h.x = (bf16)v.x; l.x = (bf16)(v.x - (float)h.x);
        h.y = (bf16)v.y; l.y = (bf16)(v.y - (float)h.y);
        h.z = (bf16)v.z; l.z = (bf16)(v.z - (float)h.z);
        h.w = (bf16)v.w; l.w = (bf16)(v.w - (float)h.w);
        *(bf16x4*)(Xhi + (long)r * Dq + idx) = h;
        *(bf16x4*)(Xlo + (long)r * Dq + idx) = l;
    }
    __syncthreads();
    int out = threadIdx.x & 31, part = threadIdx.x >> 5;
    int col = out & 15;
    const float* W = (out < 16) ? Wgk1 : Wg1;
    float s = 0.f;
    for (int kk = part; kk < Dq; kk += 8)
        s += sx[kk] * W[kk * 16 + col];
    red[out][part] = s;
    __syncthreads();
    if (threadIdx.x < 32) {
        float t = 0.f;
#pragma unroll
        for (int p = 0; p < 8; p++) t += red[threadIdx.x][p];
        int c = threadIdx.x & 15;
        if (threadIdx.x < 16) t_gk[r * 16 + c] = t;
        else                  t_g [r * 16 + c] = t;
    }
}

// ---------------- gk_cum: per-(b,h,chunk) gk -> logsigmoid -> cumsum G + dec ----------------
// G layout: [blk][t(64)][d(64)] contiguous, blk = (b*16+h)*32 + c
__global__ __launch_bounds__(256) void gk_cum(const float* __restrict__ t_gk,
                                              const float* __restrict__ Wgk2,
                                              const float* __restrict__ bgk2,
                                              float* __restrict__ G,
                                              float* __restrict__ dec) {
    __shared__ float sT[1024];    // [64][16]
    __shared__ float sW[1024];    // [16][64]
    __shared__ float sb[64];
    __shared__ float sG[64 * 64];
    int blk = blockIdx.x;
    int c = blk & 31, h = (blk >> 5) & 15, b = blk >> 9;
    int tid = threadIdx.x;
    long rowbase = (long)b * Tq + c * 64;
    {
        int idx = tid * 4;
        *(float4*)&sT[idx] = *(const float4*)(t_gk + rowbase * 16 + idx);
        int rr = idx >> 6, dd = idx & 63;
        *(float4*)&sW[idx] = *(const float4*)(Wgk2 + rr * 1024 + h * 64 + dd);
    }
    if (tid < 64) sb[tid] = bgk2[h * 64 + tid];
    __syncthreads();
    int tquad = tid >> 4, dgrp = tid & 15;
    float4 bg4 = *(float4*)&sb[dgrp * 4];
#pragma unroll
    for (int j = 0; j < 4; j++) {
        int t = tquad * 4 + j;
        float4 z = bg4;
#pragma unroll
        for (int rr = 0; rr < 16; rr++) {
            float tv = sT[t * 16 + rr];
            float4 wv = *(float4*)&sW[rr * 64 + dgrp * 4];
            z.x += tv * wv.x; z.y += tv * wv.y; z.z += tv * wv.z; z.w += tv * wv.w;
        }
        float4 o;
        o.x = (fminf(z.x, 0.f) - log1pf(__expf(-fabsf(z.x)))) * 0.0625f;
        o.y = (fminf(z.y, 0.f) - log1pf(__expf(-fabsf(z.y)))) * 0.0625f;
        o.z = (fminf(z.z, 0.f) - log1pf(__expf(-fabsf(z.z)))) * 0.0625f;
        o.w = (fminf(z.w, 0.f) - log1pf(__expf(-fabsf(z.w)))) * 0.0625f;
        *(float4*)&sG[t * 64 + dgrp * 4] = o;
    }
    __syncthreads();
    if (tid < 64) {
        float run = 0.f;
        for (int t = 0; t < 64; t++) { run += sG[t * 64 + tid]; sG[t * 64 + tid] = run; }
        dec[blk * 64 + tid] = __expf(run);
    }
    __syncthreads();
    float* Gb = G + (long)blk * 4096;
#pragma unroll
    for (int i = 0; i < 4; i++) {
        int f = tid + i * 256;
        *(float4*)(Gb + f * 4) = *(float4*)&sG[f * 4];
    }
}

// ---------------- split-3 GEMM, 4-buffer single K-loop ----------------
__global__ __launch_bounds__(256, 2) void gemm3(const bf16* __restrict__ Ahi,
                                                const bf16* __restrict__ Alo,
                                                const bf16* __restrict__ Bhi,
                                                const bf16* __restrict__ Blo,
                                                float* __restrict__ o0,
                                                float* __restrict__ o1,
                                                float* __restrict__ o2,
                                                int Ncols, int mode) {
    const int K = 2048;
    __shared__ __align__(16) bf16 sAh[128 * 32];
    __shared__ __align__(16) bf16 sAl[128 * 32];
    __shared__ __align__(16) bf16 sBh[128 * 32];
    __shared__ __align__(16) bf16 sBl[128 * 32];
    int tid = threadIdx.x;
    int wave = tid >> 6, lane = tid & 63;
    int quad = lane >> 4, l16 = lane & 15;
    int bm = blockIdx.x & 31;
    int bn = blockIdx.x >> 5;
    int wm = (wave >> 1) * 64, wn = (wave & 1) * 64;

    const int c0 = tid, c1 = tid + 256;
    const int ar0 = c0 >> 2, ak0 = (c0 & 3) * 8;
    const int ar1 = c1 >> 2, ak1 = (c1 & 3) * 8;
    const bf16* Ah = Ahi + (long)(bm * 128) * K;
    const bf16* Al = Alo + (long)(bm * 128) * K;
    const bf16* Bh = Bhi + (long)(bn * 128) * K;
    const bf16* Bl = Blo + (long)(bn * 128) * K;

    f32x4 acc[4][4] = {};

    for (int k0 = 0; k0 < K; k0 += 32) {
        gl_lds16(Ah + (long)ar0 * K + k0 + ak0, sAh + c0 * 8);
        gl_lds16(Ah + (long)ar1 * K + k0 + ak1, sAh + c1 * 8);
        gl_lds16(Al + (long)ar0 * K + k0 + ak0, sAl + c0 * 8);
        gl_lds16(Al + (long)ar1 * K + k0 + ak1, sAl + c1 * 8);
        gl_lds16(Bh + (long)ar0 * K + k0 + ak0, sBh + c0 * 8);
        gl_lds16(Bh + (long)ar1 * K + k0 + ak1, sBh + c1 * 8);
        gl_lds16(Bl + (long)ar0 * K + k0 + ak0, sBl + c0 * 8);
        gl_lds16(Bl + (long)ar1 * K + k0 + ak1, sBl + c1 * 8);
        __syncthreads();
        bf16x8 ah[4], bh[4], xf[4];
#pragma unroll
        for (int i = 0; i < 4; i++)
            ah[i] = *(const bf16x8*)(sAh + (wm + i * 16 + l16) * 32 + quad * 8);
#pragma unroll
        for (int j = 0; j < 4; j++)
            bh[j] = *(const bf16x8*)(sBh + (wn + j * 16 + l16) * 32 + quad * 8);
#pragma unroll
        for (int i = 0; i < 4; i++)
#pragma unroll
            for (int j = 0; j < 4; j++)
                acc[i][j] = __builtin_amdgcn_mfma_f32_16x16x32_bf16(ah[i], bh[j], acc[i][j], 0, 0, 0);
#pragma unroll
        for (int i = 0; i < 4; i++)
            xf[i] = *(const bf16x8*)(sAl + (wm + i * 16 + l16) * 32 + quad * 8);
#pragma unroll
        for (int i = 0; i < 4; i++)
#pragma unroll
            for (int j = 0; j < 4; j++)
                acc[i][j] = __builtin_amdgcn_mfma_f32_16x16x32_bf16(xf[i], bh[j], acc[i][j], 0, 0, 0);
#pragma unroll
        for (int j = 0; j < 4; j++)
            xf[j] = *(const bf16x8*)(sBl + (wn + j * 16 + l16) * 32 + quad * 8);
#pragma unroll
        for (int i = 0; i < 4; i++)
#pragma unroll
            for (int j = 0; j < 4; j++)
                acc[i][j] = __builtin_amdgcn_mfma_f32_16x16x32_bf16(ah[i], xf[j], acc[i][j], 0, 0, 0);
        __syncthreads();
    }
#pragma unroll
    for (int i = 0; i < 4; i++)
#pragma unroll
        for (int j = 0; j < 4; j++) {
            int row0 = bm * 128 + wm + i * 16 + quad * 4;
            int col  = bn * 128 + wn + j * 16 + l16;
            if (mode == 0) {
#pragma unroll
                for (int r = 0; r < 4; r++)
                    o0[(long)(row0 + r) * Ncols + col] = acc[i][j][r];
            } else {
                float scale = (col < 1024) ? 0.125f : 1.0f;
                float* dst; int cw, cc;
                if (col < 1024)      { dst = o0; cw = 1024; cc = col; }
                else if (col < 2048) { dst = o1; cw = 1024; cc = col - 1024; }
                else                 { dst = o2; cw = 2048; cc = col - 2048; }
#pragma unroll
                for (int r = 0; r < 4; r++) {
                    float x = acc[i][j][r];
                    x = x / (1.f + __expf(-x)) * scale;
                    dst[(long)(row0 + r) * cw + cc] = x;
                }
            }
        }
}

// ---------------- GLA pass 1: per-chunk U (G precomputed) ----------------
#define ST 76
__global__ __launch_bounds__(256) void gla_pass1(const float* __restrict__ kbuf,
                                                 const float* __restrict__ vbuf,
                                                 const float* __restrict__ G,
                                                 float* __restrict__ U) {
    __shared__ float sG[64 * ST];
    __shared__ float sK[64 * ST];
    int blk = blockIdx.x;                       // (b*16+h)*32 + c
    int c = blk & 31, h = (blk >> 5) & 15, b = blk >> 9;
    int tid = threadIdx.x;
    long rowbase = (long)b * Tq + c * 64;
    const float* Gb = G + (long)blk * 4096;
#pragma unroll
    for (int i = 0; i < 4; i++) {
        int f = tid + i * 256;
        float4 v = *(const float4*)(Gb + f * 4);
        int t = f >> 4, d0 = (f & 15) * 4;
        *(float4*)&sG[t * ST + d0] = v;
    }
    __syncthreads();
#pragma unroll
    for (int i = 0; i < 16; i++) {
        int idx = tid + i * 256;
        int t = idx >> 6, d = idx & 63;
        float gl = sG[63 * ST + d];
        sK[t * ST + d] = kbuf[(rowbase + t) * 1024 + h * 64 + d] * __expf(gl - sG[t * ST + d]);
    }
    __syncthreads();
    int ty = tid >> 4, tx = tid & 15;
    float acc[4][8] = {};
    const float* vb = vbuf + rowbase * 2048 + h * 128 + tx * 8;
    for (int t = 0; t < 64; t++) {
        float4 v0 = *(const float4*)(vb + (long)t * 2048);
        float4 v1 = *(const float4*)(vb + (long)t * 2048 + 4);
        float ve[8] = {v0.x, v0.y, v0.z, v0.w, v1.x, v1.y, v1.z, v1.w};
#pragma unroll
        for (int r = 0; r < 4; r++) {
            float kd = sK[t * ST + ty * 4 + r];
#pragma unroll
            for (int e = 0; e < 8; e++) acc[r][e] += kd * ve[e];
        }
    }
    float* Ub = U + (long)blk * 8192 + (ty * 4) * 128 + tx * 8;
#pragma unroll
    for (int r = 0; r < 4; r++) {
        float4 o0 = {acc[r][0], acc[r][1], acc[r][2], acc[r][3]};
        float4 o1 = {acc[r][4], acc[r][5], acc[r][6], acc[r][7]};
        *(float4*)(Ub + r * 128)     = o0;
        *(float4*)(Ub + r * 128 + 4) = o1;
    }
}

// ---------------- GLA pass 2: scan over chunks (in-place U -> S_prev) ----------------
__global__ __launch_bounds__(256) void gla_pass2(float* __restrict__ U,
                                                 const float* __restrict__ dec) {
    int bh = blockIdx.x >> 5;
    int base = (blockIdx.x & 31) * 256 + threadIdx.x;   // 0..8191
    int d = base >> 7;
    float S = 0.f;
    long off = (long)bh * NCq * 8192 + base;
    for (int c = 0; c < NCq; c++) {
        float u = U[off + (long)c * 8192];
        float dc = dec[(bh * NCq + c) * 64 + d];
        U[off + (long)c * 8192] = S;       // state BEFORE chunk c
        S = S * dc + u;
    }
}

// ---------------- GLA pass 3: o = qg@S_prev + tril(qg kg^T)@v, fused RMS-norm+gate -> bf16 hi/lo --------
__global__ __launch_bounds__(256) void gla_pass3(const float* __restrict__ qbuf,
                                                 const float* __restrict__ kbuf,
                                                 const float* __restrict__ vbuf,
                                                 const float* __restrict__ G,
                                                 const float* __restrict__ t_g,
                                                 const float* __restrict__ Wg2,
                                                 const float* __restrict__ bg2,
                                                 const float* __restrict__ gnw,
                                                 const float* __restrict__ Sbuf,
                                                 bf16* __restrict__ Ohi,
                                                 bf16* __restrict__ Olo) {
    __shared__ float sQ[64 * ST];
    __shared__ float sK[64 * ST];
    __shared__ float sA[64 * ST];   // G, then A
    int blk = blockIdx.x;
    int c = blk & 31, h = (blk >> 5) & 15, b = blk >> 9;
    int tid = threadIdx.x;
    long rowbase = (long)b * Tq + c * 64;
    const float* Gb = G + (long)blk * 4096;
#pragma unroll
    for (int i = 0; i < 4; i++) {
        int f = tid + i * 256;
        float4 v = *(const float4*)(Gb + f * 4);
        int t = f >> 4, d0 = (f & 15) * 4;
        *(float4*)&sA[t * ST + d0] = v;
    }
    __syncthreads();
#pragma unroll
    for (int i = 0; i < 16; i++) {
        int idx = tid + i * 256;
        int t = idx >> 6, d = idx & 63;
        float Gv = sA[t * ST + d];
        long g = (rowbase + t) * 1024 + h * 64 + d;
        sQ[t * ST + d] = qbuf[g] * __expf(Gv);
        sK[t * ST + d] = kbuf[g] * __expf(-Gv);
    }
    __syncthreads();
    int ty = tid >> 4, tx = tid & 15;
    // A = tril(sQ sK^T)
    {
        float a[4][4] = {};
        for (int d4 = 0; d4 < 16; d4++) {
            float4 qv[4], kv[4];
#pragma unroll
            for (int r = 0; r < 4; r++) qv[r] = *(const float4*)&sQ[(ty * 4 + r) * ST + d4 * 4];
#pragma unroll
            for (int cc = 0; cc < 4; cc++) kv[cc] = *(const float4*)&sK[(tx * 4 + cc) * ST + d4 * 4];
#pragma unroll
            for (int r = 0; r < 4; r++)
#pragma unroll
                for (int cc = 0; cc < 4; cc++)
                    a[r][cc] += qv[r].x * kv[cc].x + qv[r].y * kv[cc].y +
                                qv[r].z * kv[cc].z + qv[r].w * kv[cc].w;
        }
#pragma unroll
        for (int r = 0; r < 4; r++) {
            int ii = ty * 4 + r;
            float4 row;
            row.x = (tx * 4 + 0 <= ii) ? a[r][0] : 0.f;
            row.y = (tx * 4 + 1 <= ii) ? a[r][1] : 0.f;
            row.z = (tx * 4 + 2 <= ii) ? a[r][2] : 0.f;
            row.w = (tx * 4 + 3 <= ii) ? a[r][3] : 0.f;
            *(float4*)&sA[ii * ST + tx * 4] = row;
        }
    }
    __syncthreads();
    // stage gate tables into sK overlay (sK's last read was A-compute, fenced above)
    float* sWg2v = sK;          // 16*128
    float* sbg   = sK + 2048;   // 128
    {
#pragma unroll
        for (int i = 0; i < 2; i++) {
            int idx = tid * 4 + i * 1024;
            int rr = idx >> 7, ee = idx & 127;
            *(float4*)&sWg2v[idx] = *(const float4*)(Wg2 + (long)rr * 2048 + h * 128 + ee);
        }
        if (tid < 128) sbg[tid] = bg2[h * 128 + tid];
    }
    // o accumulation (reads sQ, sA, global — not the sK overlay)
    float acc[4][8] = {};
    const float* Sb = Sbuf + (long)blk * 8192 + tx * 8;
    for (int d = 0; d < 64; d++) {
        float4 s0 = *(const float4*)(Sb + d * 128);
        float4 s1 = *(const float4*)(Sb + d * 128 + 4);
        float se[8] = {s0.x, s0.y, s0.z, s0.w, s1.x, s1.y, s1.z, s1.w};
#pragma unroll
        for (int r = 0; r < 4; r++) {
            float qv = sQ[(ty * 4 + r) * ST + d];
#pragma unroll
            for (int e = 0; e < 8; e++) acc[r][e] += qv * se[e];
        }
    }
    const float* vb = vbuf + rowbase * 2048 + h * 128 + tx * 8;
    for (int j = 0; j < ty * 4 + 4; j++) {
        float4 v0 = *(const float4*)(vb + (long)j * 2048);
        float4 v1 = *(const float4*)(vb + (long)j * 2048 + 4);
        float ve[8] = {v0.x, v0.y, v0.z, v0.w, v1.x, v1.y, v1.z, v1.w};
#pragma unroll
        for (int r = 0; r < 4; r++) {
            float av = sA[(ty * 4 + r) * ST + j];
#pragma unroll
            for (int e = 0; e < 8; e++) acc[r][e] += av * ve[e];
        }
    }
    __syncthreads();   // gate tables visible
    // fused epilogue: RMS-norm over DV=128 + gnw + sigmoid gate, vectorized LDS reads
    float4 gn0 = *(const float4*)(gnw + tx * 8);
    float4 gn1 = *(const float4*)(gnw + tx * 8 + 4);
    float4 bg0 = *(float4*)&sbg[tx * 8];
    float4 bg1 = *(float4*)&sbg[tx * 8 + 4];
#pragma unroll
    for (int half = 0; half < 2; half++) {
        float tg[2][16];
#pragma unroll
        for (int rh = 0; rh < 2; rh++) {
            const float* tgp = t_g + (rowbase + ty * 4 + half * 2 + rh) * 16;
#pragma unroll
            for (int q4 = 0; q4 < 4; q4++)
                *(float4*)&tg[rh][q4 * 4] = *(const float4*)(tgp + q4 * 4);
        }
        float g[2][8];
#pragma unroll
        for (int rh = 0; rh < 2; rh++) {
            g[rh][0] = bg0.x; g[rh][1] = bg0.y; g[rh][2] = bg0.z; g[rh][3] = bg0.w;
            g[rh][4] = bg1.x; g[rh][5] = bg1.y; g[rh][6] = bg1.z; g[rh][7] = bg1.w;
        }
#pragma unroll
        for (int rr = 0; rr < 16; rr++) {
            float4 w0 = *(float4*)&sWg2v[rr * 128 + tx * 8];
            float4 w1 = *(float4*)&sWg2v[rr * 128 + tx * 8 + 4];
#pragma unroll
            for (int rh = 0; rh < 2; rh++) {
                float t = tg[rh][rr];
                g[rh][0] += t * w0.x; g[rh][1] += t * w0.y; g[rh][2] += t * w0.z; g[rh][3] += t * w0.w;
                g[rh][4] += t * w1.x; g[rh][5] += t * w1.y; g[rh][6] += t * w1.z; g[rh][7] += t * w1.w;
            }
        }
        float gw[8] = {gn0.x, gn0.y, gn0.z, gn0.w, gn1.x, gn1.y, gn1.z, gn1.w};
#pragma unroll
        for (int rh = 0; rh < 2; rh++) {
            int r = half * 2 + rh;
            int ii = ty * 4 + r;
            float ss = 0.f;
#pragma unroll
            for (int e = 0; e < 8; e++) ss += acc[r][e] * acc[r][e];
            ss += __shfl_xor(ss, 1);
            ss += __shfl_xor(ss, 2);
            ss += __shfl_xor(ss, 4);
            ss += __shfl_xor(ss, 8);
            float scale = rsqrtf(ss * (1.f / 128.f) + 1e-5f);
            bf16x8 hv, lv;
#pragma unroll
            for (int e = 0; e < 8; e++) {
                float y = acc[r][e] * scale * gw[e] / (1.f + __expf(-g[rh][e]));
                bf16 hh = (bf16)y;
                hv[e] = hh;
                lv[e] = (bf16)(y - (float)hh);
            }
            long off = (rowbase + ii) * 2048 + h * 128 + tx * 8;
            *(bf16x8*)(Ohi + off) = hv;
            *(bf16x8*)(Olo + off) = lv;
        }
    }
}

extern "C" void kernel_launch(void* const* d_in, const int* in_sizes, int n_in,
                              void* d_out, int out_size, void* d_ws, size_t ws_size,
                              hipStream_t stream) {
    const float* hs   = (const float*)d_in[0];
    const float* Wq   = (const float*)d_in[1];
    const float* Wk   = (const float*)d_in[2];
    const float* Wv   = (const float*)d_in[3];
    const float* Wgk1 = (const float*)d_in[4];
    const float* Wgk2 = (const float*)d_in[5];
    const float* bgk2 = (const float*)d_in[6];
    const float* Wg1  = (const float*)d_in[7];
    const float* Wg2  = (const float*)d_in[8];
    const float* bg2  = (const float*)d_in[9];
    const float* Wo   = (const float*)d_in[10];
    const float* gnw  = (const float*)d_in[11];

    char* w = (char*)d_ws;
    auto alloc = [&](size_t bytes) {
        char* p = w; w += (bytes + 255) & ~size_t(255); return (void*)p;
    };
    bf16*  Xhi    = (bf16*) alloc((size_t)Mq * Dq * 2);        // 16 MB (reused for Ohi)
    bf16*  Xlo    = (bf16*) alloc((size_t)Mq * Dq * 2);        // 16 MB (reused for Olo)
    bf16*  WqkvThi= (bf16*) alloc((size_t)4096 * 2048 * 2);    // 16 MB  [q|k|v] rows
    bf16*  WqkvTlo= (bf16*) alloc((size_t)4096 * 2048 * 2);    // 16 MB
    bf16*  WoThi  = (bf16*) alloc((size_t)2048 * 2048 * 2);    // 8 MB
    bf16*  WoTlo  = (bf16*) alloc((size_t)2048 * 2048 * 2);    // 8 MB
    float* qb     = (float*)alloc((size_t)Mq * 1024 * 4);      // 16 MB
    float* kb     = (float*)alloc((size_t)Mq * 1024 * 4);      // 16 MB
    float* vb     = (float*)alloc((size_t)Mq * 2048 * 4);      // 32 MB
    float* t_gk   = (float*)alloc((size_t)Mq * 16 * 4);
    float* t_g    = (float*)alloc((size_t)Mq * 16 * 4);
    float* U      = (float*)alloc((size_t)NBH * NCq * 8192 * 4); // 33.5 MB (Sbuf in-place)
    float* dec    = (float*)alloc((size_t)NBH * NCq * 64 * 4);
    float* Gbuf   = (float*)alloc((size_t)NBH * NCq * 4096 * 4); // 16.8 MB

    trans_all<<<12288, 256, 0, stream>>>(Wq, Wk, Wv, Wo, WqkvThi, WqkvTlo, WoThi, WoTlo);
    hs_prep<<<Mq, 256, 0, stream>>>(hs, Wgk1, Wg1, Xhi, Xlo, t_gk, t_g);
    gk_cum<<<NBH * NCq, 256, 0, stream>>>(t_gk, Wgk2, bgk2, Gbuf, dec);

    // fused q|k|v GEMM: N = 4096, 32x32 = 1024 blocks
    gemm3<<<32 * 32, 256, 0, stream>>>(Xhi, Xlo, WqkvThi, WqkvTlo, qb, kb, vb, 4096, 1);

    gla_pass1<<<NBH * NCq, 256, 0, stream>>>(kb, vb, Gbuf, U);
    gla_pass2<<<NBH * NCq, 256, 0, stream>>>(U, dec);
    gla_pass3<<<NBH * NCq, 256, 0, stream>>>(qb, kb, vb, Gbuf, t_g, Wg2, bg2, gnw, U, Xhi, Xlo);

    // out GEMM: N = 2048, 32x16 = 512 blocks
    gemm3<<<32 * 16, 256, 0, stream>>>(Xhi, Xlo, WoThi, WoTlo, (float*)d_out, nullptr, nullptr, 2048, 0);
}

// Round 6
// 560.897 us; speedup vs baseline: 1.4363x; 1.3772x over previous
//
#include <hip/hip_runtime.h>
#include <cstdint>

// Problem constants
#define Bq   2
#define Tq   2048
#define Dq   2048
#define Hq   16
#define DKq  64
#define DVq  128
#define Cq   64          // chunk len
#define NCq  32          // chunks
#define Mq   4096        // B*T
#define NBH  32          // B*H

typedef _Float16 f16;
typedef f16 f16x4 __attribute__((ext_vector_type(4)));
typedef f16 f16x8 __attribute__((ext_vector_type(8)));
typedef float f32x4 __attribute__((ext_vector_type(4)));

__device__ __forceinline__ void gl_lds16(const void* g, void* l) {
    __builtin_amdgcn_global_load_lds(
        (const __attribute__((address_space(1))) uint32_t*)g,
        (__attribute__((address_space(3))) uint32_t*)l, 16, 0, 0);
}

// ---------------- merged weight transpose to f16: all 4 weights in one dispatch ----------------
__global__ __launch_bounds__(256) void trans_all(const float* __restrict__ Wq,
                                                 const float* __restrict__ Wk,
                                                 const float* __restrict__ Wv,
                                                 const float* __restrict__ Wo,
                                                 f16* __restrict__ Qkv, f16* __restrict__ WoT) {
    __shared__ float s[32][33];
    int blk = blockIdx.x;
    const float* W; f16* Dh; int N, nt, kt; long rowoff;
    if (blk < 2048)      { W = Wq; N = 1024; int t = blk;        nt = t & 31; kt = t >> 5; Dh = Qkv; rowoff = 0; }
    else if (blk < 4096) { W = Wk; N = 1024; int t = blk - 2048; nt = t & 31; kt = t >> 5; Dh = Qkv; rowoff = 1024; }
    else if (blk < 8192) { W = Wv; N = 2048; int t = blk - 4096; nt = t & 63; kt = t >> 6; Dh = Qkv; rowoff = 2048; }
    else                 { W = Wo; N = 2048; int t = blk - 8192; nt = t & 63; kt = t >> 6; Dh = WoT; rowoff = 0; }
    int tx = threadIdx.x & 31, ty = threadIdx.x >> 5;   // 32 x 8
#pragma unroll
    for (int i = 0; i < 4; i++) {
        int k = kt * 32 + ty + i * 8;
        int n = nt * 32 + tx;
        s[tx][ty + i * 8] = W[(long)k * N + n];
    }
    __syncthreads();
#pragma unroll
    for (int i = 0; i < 4; i++) {
        int n = nt * 32 + ty + i * 8;
        int k = kt * 32 + tx;
        Dh[(rowoff + n) * 2048L + k] = (f16)s[ty + i * 8][tx];
    }
}

// ---------------- fused: hs -> f16 X + rank-16 factors t_gk,t_g ----------------
__global__ __launch_bounds__(256) void hs_prep(const float* __restrict__ X,
                                               const float* __restrict__ Wgk1,
                                               const float* __restrict__ Wg1,
                                               f16* __restrict__ Xh,
                                               float* __restrict__ t_gk, float* __restrict__ t_g) {
    __shared__ float sx[2048];
    __shared__ float red[32][9];
    int r = blockIdx.x;
    const float* xr = X + (long)r * Dq;
#pragma unroll
    for (int i = 0; i < 2; i++) {
        int idx = (threadIdx.x + i * 256) * 4;
        float4 v = *(const float4*)(xr + idx);
        *(float4*)&sx[idx] = v;
        f16x4 h;
        h.x = (f16)v.x; h.y = (f16)v.y; h.z = (f16)v.z; h.w = (f16)v.w;
        *(f16x4*)(Xh + (long)r * Dq + idx) = h;
    }
    __syncthreads();
    int out = threadIdx.x & 31, part = threadIdx.x >> 5;
    int col = out & 15;
    const float* W = (out < 16) ? Wgk1 : Wg1;
    float s = 0.f;
    for (int kk = part; kk < Dq; kk += 8)
        s += sx[kk] * W[kk * 16 + col];
    red[out][part] = s;
    __syncthreads();
    if (threadIdx.x < 32) {
        float t = 0.f;
#pragma unroll
        for (int p = 0; p < 8; p++) t += red[threadIdx.x][p];
        int c = threadIdx.x & 15;
        if (threadIdx.x < 16) t_gk[r * 16 + c] = t;
        else                  t_g [r * 16 + c] = t;
    }
}

// ---------------- gk_cum: per-(b,h,chunk) gk -> logsigmoid -> cumsum G + dec ----------------
__global__ __launch_bounds__(256) void gk_cum(const float* __restrict__ t_gk,
                                              const float* __restrict__ Wgk2,
                                              const float* __restrict__ bgk2,
                                              float* __restrict__ G,
                                              float* __restrict__ dec) {
    __shared__ float sT[1024];    // [64][16]
    __shared__ float sW[1024];    // [16][64]
    __shared__ float sb[64];
    __shared__ float sG[64 * 64];
    int blk = blockIdx.x;
    int c = blk & 31, h = (blk >> 5) & 15, b = blk >> 9;
    int tid = threadIdx.x;
    long rowbase = (long)b * Tq + c * 64;
    {
        int idx = tid * 4;
        *(float4*)&sT[idx] = *(const float4*)(t_gk + rowbase * 16 + idx);
        int rr = idx >> 6, dd = idx & 63;
        *(float4*)&sW[idx] = *(const float4*)(Wgk2 + rr * 1024 + h * 64 + dd);
    }
    if (tid < 64) sb[tid] = bgk2[h * 64 + tid];
    __syncthreads();
    int tquad = tid >> 4, dgrp = tid & 15;
    float4 bg4 = *(float4*)&sb[dgrp * 4];
#pragma unroll
    for (int j = 0; j < 4; j++) {
        int t = tquad * 4 + j;
        float4 z = bg4;
#pragma unroll
        for (int rr = 0; rr < 16; rr++) {
            float tv = sT[t * 16 + rr];
            float4 wv = *(float4*)&sW[rr * 64 + dgrp * 4];
            z.x += tv * wv.x; z.y += tv * wv.y; z.z += tv * wv.z; z.w += tv * wv.w;
        }
        float4 o;
        o.x = (fminf(z.x, 0.f) - log1pf(__expf(-fabsf(z.x)))) * 0.0625f;
        o.y = (fminf(z.y, 0.f) - log1pf(__expf(-fabsf(z.y)))) * 0.0625f;
        o.z = (fminf(z.z, 0.f) - log1pf(__expf(-fabsf(z.z)))) * 0.0625f;
        o.w = (fminf(z.w, 0.f) - log1pf(__expf(-fabsf(z.w)))) * 0.0625f;
        *(float4*)&sG[t * 64 + dgrp * 4] = o;
    }
    __syncthreads();
    if (tid < 64) {
        float run = 0.f;
        for (int t = 0; t < 64; t++) { run += sG[t * 64 + tid]; sG[t * 64 + tid] = run; }
        dec[blk * 64 + tid] = __expf(run);
    }
    __syncthreads();
    float* Gb = G + (long)blk * 4096;
#pragma unroll
    for (int i = 0; i < 4; i++) {
        int f = tid + i * 256;
        *(float4*)(Gb + f * 4) = *(float4*)&sG[f * 4];
    }
}

// ---------------- single-pass fp16 GEMM (m97 structure) ----------------
// mode 0: plain write to o0 [M][Ncols]; mode 1: qkv routing with silu (+0.125 for q cols)
__global__ __launch_bounds__(256, 2) void gemm_f16(const f16* __restrict__ A,
                                                   const f16* __restrict__ Bt,
                                                   float* __restrict__ o0,
                                                   float* __restrict__ o1,
                                                   float* __restrict__ o2,
                                                   int Ncols, int mode) {
    const int K = 2048;
    __shared__ __align__(16) f16 sA[128 * 32];
    __shared__ __align__(16) f16 sB[128 * 32];
    int tid = threadIdx.x;
    int wave = tid >> 6, lane = tid & 63;
    int quad = lane >> 4, l16 = lane & 15;
    int bm = blockIdx.x & 31;
    int bn = blockIdx.x >> 5;
    int wm = (wave >> 1) * 64, wn = (wave & 1) * 64;

    const int c0 = tid, c1 = tid + 256;
    const int ar0 = c0 >> 2, ak0 = (c0 & 3) * 8;
    const int ar1 = c1 >> 2, ak1 = (c1 & 3) * 8;
    const f16* Ab = A  + (long)(bm * 128) * K;
    const f16* Bb = Bt + (long)(bn * 128) * K;

    f32x4 acc[4][4] = {};

    for (int k0 = 0; k0 < K; k0 += 32) {
        gl_lds16(Ab + (long)ar0 * K + k0 + ak0, sA + c0 * 8);
        gl_lds16(Ab + (long)ar1 * K + k0 + ak1, sA + c1 * 8);
        gl_lds16(Bb + (long)ar0 * K + k0 + ak0, sB + c0 * 8);
        gl_lds16(Bb + (long)ar1 * K + k0 + ak1, sB + c1 * 8);
        __syncthreads();
        f16x8 af[4], bfr[4];
#pragma unroll
        for (int i = 0; i < 4; i++)
            af[i] = *(const f16x8*)(sA + (wm + i * 16 + l16) * 32 + quad * 8);
#pragma unroll
        for (int j = 0; j < 4; j++)
            bfr[j] = *(const f16x8*)(sB + (wn + j * 16 + l16) * 32 + quad * 8);
#pragma unroll
        for (int i = 0; i < 4; i++)
#pragma unroll
            for (int j = 0; j < 4; j++)
                acc[i][j] = __builtin_amdgcn_mfma_f32_16x16x32_f16(af[i], bfr[j], acc[i][j], 0, 0, 0);
        __syncthreads();
    }
#pragma unroll
    for (int i = 0; i < 4; i++)
#pragma unroll
        for (int j = 0; j < 4; j++) {
            int row0 = bm * 128 + wm + i * 16 + quad * 4;
            int col  = bn * 128 + wn + j * 16 + l16;
            if (mode == 0) {
#pragma unroll
                for (int r = 0; r < 4; r++)
                    o0[(long)(row0 + r) * Ncols + col] = acc[i][j][r];
            } else {
                float scale = (col < 1024) ? 0.125f : 1.0f;
                float* dst; int cw, cc;
                if (col < 1024)      { dst = o0; cw = 1024; cc = col; }
                else if (col < 2048) { dst = o1; cw = 1024; cc = col - 1024; }
                else                 { dst = o2; cw = 2048; cc = col - 2048; }
#pragma unroll
                for (int r = 0; r < 4; r++) {
                    float x = acc[i][j][r];
                    x = x / (1.f + __expf(-x)) * scale;
                    dst[(long)(row0 + r) * cw + cc] = x;
                }
            }
        }
}

// ---------------- GLA pass 1: per-chunk U (G precomputed) ----------------
#define ST 76
__global__ __launch_bounds__(256) void gla_pass1(const float* __restrict__ kbuf,
                                                 const float* __restrict__ vbuf,
                                                 const float* __restrict__ G,
                                                 float* __restrict__ U) {
    __shared__ float sG[64 * ST];
    __shared__ float sK[64 * ST];
    int blk = blockIdx.x;                       // (b*16+h)*32 + c
    int c = blk & 31, h = (blk >> 5) & 15, b = blk >> 9;
    int tid = threadIdx.x;
    long rowbase = (long)b * Tq + c * 64;
    const float* Gb = G + (long)blk * 4096;
#pragma unroll
    for (int i = 0; i < 4; i++) {
        int f = tid + i * 256;
        float4 v = *(const float4*)(Gb + f * 4);
        int t = f >> 4, d0 = (f & 15) * 4;
        *(float4*)&sG[t * ST + d0] = v;
    }
    __syncthreads();
#pragma unroll
    for (int i = 0; i < 16; i++) {
        int idx = tid + i * 256;
        int t = idx >> 6, d = idx & 63;
        float gl = sG[63 * ST + d];
        sK[t * ST + d] = kbuf[(rowbase + t) * 1024 + h * 64 + d] * __expf(gl - sG[t * ST + d]);
    }
    __syncthreads();
    int ty = tid >> 4, tx = tid & 15;
    float acc[4][8] = {};
    const float* vb = vbuf + rowbase * 2048 + h * 128 + tx * 8;
    for (int t = 0; t < 64; t++) {
        float kd[4];
        *(float4*)&kd[0] = *(float4*)&sK[t * ST + ty * 4];
        float4 v0 = *(const float4*)(vb + (long)t * 2048);
        float4 v1 = *(const float4*)(vb + (long)t * 2048 + 4);
        float ve[8] = {v0.x, v0.y, v0.z, v0.w, v1.x, v1.y, v1.z, v1.w};
#pragma unroll
        for (int r = 0; r < 4; r++)
#pragma unroll
            for (int e = 0; e < 8; e++) acc[r][e] += kd[r] * ve[e];
    }
    float* Ub = U + (long)blk * 8192 + (ty * 4) * 128 + tx * 8;
#pragma unroll
    for (int r = 0; r < 4; r++) {
        float4 o0 = {acc[r][0], acc[r][1], acc[r][2], acc[r][3]};
        float4 o1 = {acc[r][4], acc[r][5], acc[r][6], acc[r][7]};
        *(float4*)(Ub + r * 128)     = o0;
        *(float4*)(Ub + r * 128 + 4) = o1;
    }
}

// ---------------- GLA pass 2: scan over chunks (in-place U -> S_prev) ----------------
__global__ __launch_bounds__(256) void gla_pass2(float* __restrict__ U,
                                                 const float* __restrict__ dec) {
    int bh = blockIdx.x >> 5;
    int base = (blockIdx.x & 31) * 256 + threadIdx.x;   // 0..8191
    int d = base >> 7;
    float S = 0.f;
    long off = (long)bh * NCq * 8192 + base;
    for (int c = 0; c < NCq; c++) {
        float u = U[off + (long)c * 8192];
        float dc = dec[(bh * NCq + c) * 64 + d];
        U[off + (long)c * 8192] = S;       // state BEFORE chunk c
        S = S * dc + u;
    }
}

// ---------------- GLA pass 3: o = qg@S_prev + tril(qg kg^T)@v, fused RMS-norm+gate -> f16 --------
__global__ __launch_bounds__(256) void gla_pass3(const float* __restrict__ qbuf,
                                                 const float* __restrict__ kbuf,
                                                 const float* __restrict__ vbuf,
                                                 const float* __restrict__ G,
                                                 const float* __restrict__ t_g,
                                                 const float* __restrict__ Wg2,
                                                 const float* __restrict__ bg2,
                                                 const float* __restrict__ gnw,
                                                 const float* __restrict__ Sbuf,
                                                 f16* __restrict__ Oh) {
    __shared__ float sQ[64 * ST];
    __shared__ float sK[64 * ST];
    __shared__ float sA[64 * ST];   // G, then A
    int blk = blockIdx.x;
    int c = blk & 31, h = (blk >> 5) & 15, b = blk >> 9;
    int tid = threadIdx.x;
    long rowbase = (long)b * Tq + c * 64;
    const float* Gb = G + (long)blk * 4096;
#pragma unroll
    for (int i = 0; i < 4; i++) {
        int f = tid + i * 256;
        float4 v = *(const float4*)(Gb + f * 4);
        int t = f >> 4, d0 = (f & 15) * 4;
        *(float4*)&sA[t * ST + d0] = v;
    }
    __syncthreads();
#pragma unroll
    for (int i = 0; i < 16; i++) {
        int idx = tid + i * 256;
        int t = idx >> 6, d = idx & 63;
        float Gv = sA[t * ST + d];
        long g = (rowbase + t) * 1024 + h * 64 + d;
        sQ[t * ST + d] = qbuf[g] * __expf(Gv);
        sK[t * ST + d] = kbuf[g] * __expf(-Gv);
    }
    __syncthreads();
    int ty = tid >> 4, tx = tid & 15;
    // A = tril(sQ sK^T)
    {
        float a[4][4] = {};
        for (int d4 = 0; d4 < 16; d4++) {
            float4 qv[4], kv[4];
#pragma unroll
            for (int r = 0; r < 4; r++) qv[r] = *(const float4*)&sQ[(ty * 4 + r) * ST + d4 * 4];
#pragma unroll
            for (int cc = 0; cc < 4; cc++) kv[cc] = *(const float4*)&sK[(tx * 4 + cc) * ST + d4 * 4];
#pragma unroll
            for (int r = 0; r < 4; r++)
#pragma unroll
                for (int cc = 0; cc < 4; cc++)
                    a[r][cc] += qv[r].x * kv[cc].x + qv[r].y * kv[cc].y +
                                qv[r].z * kv[cc].z + qv[r].w * kv[cc].w;
        }
#pragma unroll
        for (int r = 0; r < 4; r++) {
            int ii = ty * 4 + r;
            float4 row;
            row.x = (tx * 4 + 0 <= ii) ? a[r][0] : 0.f;
            row.y = (tx * 4 + 1 <= ii) ? a[r][1] : 0.f;
            row.z = (tx * 4 + 2 <= ii) ? a[r][2] : 0.f;
            row.w = (tx * 4 + 3 <= ii) ? a[r][3] : 0.f;
            *(float4*)&sA[ii * ST + tx * 4] = row;
        }
    }
    __syncthreads();
    // stage gate tables into sK overlay (sK's last read was A-compute, fenced above)
    float* sWg2v = sK;          // 16*128
    float* sbg   = sK + 2048;   // 128
    {
#pragma unroll
        for (int i = 0; i < 2; i++) {
            int idx = tid * 4 + i * 1024;
            int rr = idx >> 7, ee = idx & 127;
            *(float4*)&sWg2v[idx] = *(const float4*)(Wg2 + (long)rr * 2048 + h * 128 + ee);
        }
        if (tid < 128) sbg[tid] = bg2[h * 128 + tid];
    }
    // o accumulation (reads sQ, sA, global — not the sK overlay); vectorized LDS
    float acc[4][8] = {};
    const float* Sb = Sbuf + (long)blk * 8192 + tx * 8;
    for (int d4 = 0; d4 < 16; d4++) {
        float qa[4][4];
#pragma unroll
        for (int r = 0; r < 4; r++)
            *(float4*)&qa[r][0] = *(float4*)&sQ[(ty * 4 + r) * ST + d4 * 4];
#pragma unroll
        for (int dd = 0; dd < 4; dd++) {
            int d = d4 * 4 + dd;
            float4 s0 = *(const float4*)(Sb + d * 128);
            float4 s1 = *(const float4*)(Sb + d * 128 + 4);
            float se[8] = {s0.x, s0.y, s0.z, s0.w, s1.x, s1.y, s1.z, s1.w};
#pragma unroll
            for (int r = 0; r < 4; r++) {
                float qv = qa[r][dd];
#pragma unroll
                for (int e = 0; e < 8; e++) acc[r][e] += qv * se[e];
            }
        }
    }
    const float* vb = vbuf + rowbase * 2048 + h * 128 + tx * 8;
    for (int j4 = 0; j4 <= ty; j4++) {
        float aa[4][4];
#pragma unroll
        for (int r = 0; r < 4; r++)
            *(float4*)&aa[r][0] = *(float4*)&sA[(ty * 4 + r) * ST + j4 * 4];
#pragma unroll
        for (int jj = 0; jj < 4; jj++) {
            int j = j4 * 4 + jj;
            float4 v0 = *(const float4*)(vb + (long)j * 2048);
            float4 v1 = *(const float4*)(vb + (long)j * 2048 + 4);
            float ve[8] = {v0.x, v0.y, v0.z, v0.w, v1.x, v1.y, v1.z, v1.w};
#pragma unroll
            for (int r = 0; r < 4; r++) {
                float av = aa[r][jj];
#pragma unroll
                for (int e = 0; e < 8; e++) acc[r][e] += av * ve[e];
            }
        }
    }
    __syncthreads();   // gate tables visible
    // fused epilogue: RMS-norm over DV=128 + gnw + sigmoid gate
    float4 gn0 = *(const float4*)(gnw + tx * 8);
    float4 gn1 = *(const float4*)(gnw + tx * 8 + 4);
    float4 bg0 = *(float4*)&sbg[tx * 8];
    float4 bg1 = *(float4*)&sbg[tx * 8 + 4];
#pragma unroll
    for (int half = 0; half < 2; half++) {
        float tg[2][16];
#pragma unroll
        for (int rh = 0; rh < 2; rh++) {
            const float* tgp = t_g + (rowbase + ty * 4 + half * 2 + rh) * 16;
#pragma unroll
            for (int q4 = 0; q4 < 4; q4++)
                *(float4*)&tg[rh][q4 * 4] = *(const float4*)(tgp + q4 * 4);
        }
        float g[2][8];
#pragma unroll
        for (int rh = 0; rh < 2; rh++) {
            g[rh][0] = bg0.x; g[rh][1] = bg0.y; g[rh][2] = bg0.z; g[rh][3] = bg0.w;
            g[rh][4] = bg1.x; g[rh][5] = bg1.y; g[rh][6] = bg1.z; g[rh][7] = bg1.w;
        }
#pragma unroll
        for (int rr = 0; rr < 16; rr++) {
            float4 w0 = *(float4*)&sWg2v[rr * 128 + tx * 8];
            float4 w1 = *(float4*)&sWg2v[rr * 128 + tx * 8 + 4];
#pragma unroll
            for (int rh = 0; rh < 2; rh++) {
                float t = tg[rh][rr];
                g[rh][0] += t * w0.x; g[rh][1] += t * w0.y; g[rh][2] += t * w0.z; g[rh][3] += t * w0.w;
                g[rh][4] += t * w1.x; g[rh][5] += t * w1.y; g[rh][6] += t * w1.z; g[rh][7] += t * w1.w;
            }
        }
        float gw[8] = {gn0.x, gn0.y, gn0.z, gn0.w, gn1.x, gn1.y, gn1.z, gn1.w};
#pragma unroll
        for (int rh = 0; rh < 2; rh++) {
            int r = half * 2 + rh;
            int ii = ty * 4 + r;
            float ss = 0.f;
#pragma unroll
            for (int e = 0; e < 8; e++) ss += acc[r][e] * acc[r][e];
            ss += __shfl_xor(ss, 1);
            ss += __shfl_xor(ss, 2);
            ss += __shfl_xor(ss, 4);
            ss += __shfl_xor(ss, 8);
            float scale = rsqrtf(ss * (1.f / 128.f) + 1e-5f);
            f16x8 hv;
#pragma unroll
            for (int e = 0; e < 8; e++) {
                float y = acc[r][e] * scale * gw[e] / (1.f + __expf(-g[rh][e]));
                hv[e] = (f16)y;
            }
            long off = (rowbase + ii) * 2048 + h * 128 + tx * 8;
            *(f16x8*)(Oh + off) = hv;
        }
    }
}

extern "C" void kernel_launch(void* const* d_in, const int* in_sizes, int n_in,
                              void* d_out, int out_size, void* d_ws, size_t ws_size,
                              hipStream_t stream) {
    const float* hs   = (const float*)d_in[0];
    const float* Wq   = (const float*)d_in[1];
    const float* Wk   = (const float*)d_in[2];
    const float* Wv   = (const float*)d_in[3];
    const float* Wgk1 = (const float*)d_in[4];
    const float* Wgk2 = (const float*)d_in[5];
    const float* bgk2 = (const float*)d_in[6];
    const float* Wg1  = (const float*)d_in[7];
    const float* Wg2  = (const float*)d_in[8];
    const float* bg2  = (const float*)d_in[9];
    const float* Wo   = (const float*)d_in[10];
    const float* gnw  = (const float*)d_in[11];

    char* w = (char*)d_ws;
    auto alloc = [&](size_t bytes) {
        char* p = w; w += (bytes + 255) & ~size_t(255); return (void*)p;
    };
    f16*   Xh     = (f16*)  alloc((size_t)Mq * Dq * 2);        // 16 MB (reused for O)
    f16*   WqkvT  = (f16*)  alloc((size_t)4096 * 2048 * 2);    // 16 MB  [q|k|v] rows
    f16*   WoT    = (f16*)  alloc((size_t)2048 * 2048 * 2);    // 8 MB
    float* qb     = (float*)alloc((size_t)Mq * 1024 * 4);      // 16 MB
    float* kb     = (float*)alloc((size_t)Mq * 1024 * 4);      // 16 MB
    float* vb     = (float*)alloc((size_t)Mq * 2048 * 4);      // 32 MB
    float* t_gk   = (float*)alloc((size_t)Mq * 16 * 4);
    float* t_g    = (float*)alloc((size_t)Mq * 16 * 4);
    float* U      = (float*)alloc((size_t)NBH * NCq * 8192 * 4); // 33.5 MB (Sbuf in-place)
    float* dec    = (float*)alloc((size_t)NBH * NCq * 64 * 4);
    float* Gbuf   = (float*)alloc((size_t)NBH * NCq * 4096 * 4); // 16.8 MB

    trans_all<<<12288, 256, 0, stream>>>(Wq, Wk, Wv, Wo, WqkvT, WoT);
    hs_prep<<<Mq, 256, 0, stream>>>(hs, Wgk1, Wg1, Xh, t_gk, t_g);
    gk_cum<<<NBH * NCq, 256, 0, stream>>>(t_gk, Wgk2, bgk2, Gbuf, dec);

    // fused q|k|v GEMM: N = 4096, 32x32 = 1024 blocks
    gemm_f16<<<32 * 32, 256, 0, stream>>>(Xh, WqkvT, qb, kb, vb, 4096, 1);

    gla_pass1<<<NBH * NCq, 256, 0, stream>>>(kb, vb, Gbuf, U);
    gla_pass2<<<NBH * NCq, 256, 0, stream>>>(U, dec);
    // pass3 writes normalized+gated output directly as f16 into Xh (X dead after qkv GEMM)
    gla_pass3<<<NBH * NCq, 256, 0, stream>>>(qb, kb, vb, Gbuf, t_g, Wg2, bg2, gnw, U, Xh);

    // out GEMM: N = 2048, 32x16 = 512 blocks
    gemm_f16<<<32 * 16, 256, 0, stream>>>(Xh, WoT, (float*)d_out, nullptr, nullptr, 2048, 0);
}

// Round 7
// 465.431 us; speedup vs baseline: 1.7309x; 1.2051x over previous
//
#include <hip/hip_runtime.h>
#include <cstdint>

// Problem constants
#define Bq   2
#define Tq   2048
#define Dq   2048
#define Hq   16
#define DKq  64
#define DVq  128
#define Cq   64          // chunk len
#define NCq  32          // chunks
#define Mq   4096        // B*T
#define NBH  32          // B*H

typedef _Float16 f16;
typedef f16 f16x4 __attribute__((ext_vector_type(4)));
typedef f16 f16x8 __attribute__((ext_vector_type(8)));
typedef float f32x4 __attribute__((ext_vector_type(4)));

__device__ __forceinline__ void gl_lds16(const void* g, void* l) {
    __builtin_amdgcn_global_load_lds(
        (const __attribute__((address_space(1))) uint32_t*)g,
        (__attribute__((address_space(3))) uint32_t*)l, 16, 0, 0);
}

// ---------------- merged weight transpose to f16 + low-rank cols + zero-pad ----------------
// Qkv layout [4224][2048]: rows 0..1023 Wq^T, 1024..2047 Wk^T, 2048..4095 Wv^T,
// 4096..4111 Wgk1^T, 4112..4127 Wg1^T, 4128..4223 zeros. WoT [2048][2048].
__global__ __launch_bounds__(256) void trans_all(const float* __restrict__ Wq,
                                                 const float* __restrict__ Wk,
                                                 const float* __restrict__ Wv,
                                                 const float* __restrict__ Wo,
                                                 const float* __restrict__ Wgk1,
                                                 const float* __restrict__ Wg1,
                                                 f16* __restrict__ Qkv, f16* __restrict__ WoT) {
    __shared__ float sh[4096];
    int blk = blockIdx.x;
    int tid = threadIdx.x;
    if (blk < 12288) {
        const float* W; f16* Dh; int N, nt, kt; long rowoff;
        if (blk < 2048)      { W = Wq; N = 1024; int t = blk;        nt = t & 31; kt = t >> 5; Dh = Qkv; rowoff = 0; }
        else if (blk < 4096) { W = Wk; N = 1024; int t = blk - 2048; nt = t & 31; kt = t >> 5; Dh = Qkv; rowoff = 1024; }
        else if (blk < 8192) { W = Wv; N = 2048; int t = blk - 4096; nt = t & 63; kt = t >> 6; Dh = Qkv; rowoff = 2048; }
        else                 { W = Wo; N = 2048; int t = blk - 8192; nt = t & 63; kt = t >> 6; Dh = WoT; rowoff = 0; }
        int tx = tid & 31, ty = tid >> 5;   // 32 x 8
#pragma unroll
        for (int i = 0; i < 4; i++) {
            int k = kt * 32 + ty + i * 8;
            int n = nt * 32 + tx;
            sh[tx * 33 + ty + i * 8] = W[(long)k * N + n];
        }
        __syncthreads();
#pragma unroll
        for (int i = 0; i < 4; i++) {
            int n = nt * 32 + ty + i * 8;
            int k = kt * 32 + tx;
            Dh[(rowoff + n) * 2048L + k] = (f16)sh[(ty + i * 8) * 33 + tx];
        }
    } else if (blk < 12304) {
        // Wgk1 / Wg1 [2048][16] -> Qkv rows 4096..4127, k-slice of 256
        const float* Ws = (blk < 12296) ? Wgk1 : Wg1;
        long rowo = (blk < 12296) ? 4096 : 4112;
        int kb = ((blk - 12288) & 7) * 256;
#pragma unroll
        for (int i = 0; i < 4; i++) {
            int e = (tid + i * 256) * 4;            // 0..4095
            int kk = e >> 4, n = e & 15;
            *(float4*)&sh[e] = *(const float4*)(Ws + (long)(kb + kk) * 16 + n);
        }
        __syncthreads();
        int n = tid >> 4, k16 = (tid & 15) * 16;
        f16x8 o0, o1;
#pragma unroll
        for (int j = 0; j < 8; j++) {
            o0[j] = (f16)sh[(k16 + j) * 16 + n];
            o1[j] = (f16)sh[(k16 + 8 + j) * 16 + n];
        }
        *(f16x8*)(Qkv + (rowo + n) * 2048L + kb + k16)     = o0;
        *(f16x8*)(Qkv + (rowo + n) * 2048L + kb + k16 + 8) = o1;
    } else {
        // zero rows 4128..4223
        int rz = 4128 + (blk - 12304) * 4;
        f16x8 z = {};
#pragma unroll
        for (int i = 0; i < 4; i++)
            *(f16x8*)(Qkv + (long)(rz + i) * 2048 + tid * 8) = z;
    }
}

// ---------------- pure f32 -> f16 convert ----------------
__global__ __launch_bounds__(256) void hs_conv(const float* __restrict__ in,
                                               f16* __restrict__ out) {
    long i = ((long)blockIdx.x * 256 + threadIdx.x) * 8;
    float4 a = *(const float4*)(in + i);
    float4 b = *(const float4*)(in + i + 4);
    f16x8 h;
    h[0] = (f16)a.x; h[1] = (f16)a.y; h[2] = (f16)a.z; h[3] = (f16)a.w;
    h[4] = (f16)b.x; h[5] = (f16)b.y; h[6] = (f16)b.z; h[7] = (f16)b.w;
    *(f16x8*)(out + i) = h;
}

// ---------------- gk_cum: per-(b,h,chunk) gk -> logsigmoid -> cumsum G + dec ----------------
__global__ __launch_bounds__(256) void gk_cum(const float* __restrict__ t_gk,
                                              const float* __restrict__ Wgk2,
                                              const float* __restrict__ bgk2,
                                              float* __restrict__ G,
                                              float* __restrict__ dec) {
    __shared__ float sT[1024];    // [64][16]
    __shared__ float sW[1024];    // [16][64]
    __shared__ float sb[64];
    __shared__ float sG[64 * 64];
    int blk = blockIdx.x;
    int c = blk & 31, h = (blk >> 5) & 15, b = blk >> 9;
    int tid = threadIdx.x;
    long rowbase = (long)b * Tq + c * 64;
    {
        int idx = tid * 4;
        *(float4*)&sT[idx] = *(const float4*)(t_gk + rowbase * 16 + idx);
        int rr = idx >> 6, dd = idx & 63;
        *(float4*)&sW[idx] = *(const float4*)(Wgk2 + rr * 1024 + h * 64 + dd);
    }
    if (tid < 64) sb[tid] = bgk2[h * 64 + tid];
    __syncthreads();
    int tquad = tid >> 4, dgrp = tid & 15;
    float4 bg4 = *(float4*)&sb[dgrp * 4];
#pragma unroll
    for (int j = 0; j < 4; j++) {
        int t = tquad * 4 + j;
        float4 z = bg4;
#pragma unroll
        for (int rr = 0; rr < 16; rr++) {
            float tv = sT[t * 16 + rr];
            float4 wv = *(float4*)&sW[rr * 64 + dgrp * 4];
            z.x += tv * wv.x; z.y += tv * wv.y; z.z += tv * wv.z; z.w += tv * wv.w;
        }
        float4 o;
        o.x = (fminf(z.x, 0.f) - log1pf(__expf(-fabsf(z.x)))) * 0.0625f;
        o.y = (fminf(z.y, 0.f) - log1pf(__expf(-fabsf(z.y)))) * 0.0625f;
        o.z = (fminf(z.z, 0.f) - log1pf(__expf(-fabsf(z.z)))) * 0.0625f;
        o.w = (fminf(z.w, 0.f) - log1pf(__expf(-fabsf(z.w)))) * 0.0625f;
        *(float4*)&sG[t * 64 + dgrp * 4] = o;
    }
    __syncthreads();
    if (tid < 64) {
        float run = 0.f;
        for (int t = 0; t < 64; t++) { run += sG[t * 64 + tid]; sG[t * 64 + tid] = run; }
        dec[blk * 64 + tid] = __expf(run);
    }
    __syncthreads();
    float* Gb = G + (long)blk * 4096;
#pragma unroll
    for (int i = 0; i < 4; i++) {
        int f = tid + i * 256;
        *(float4*)(Gb + f * 4) = *(float4*)&sG[f * 4];
    }
}

// ---------------- single-pass fp16 GEMM (m97 structure) ----------------
// mode 0: plain write to o0 [M][Ncols]
// mode 1: qkv+lowrank routing: col<1024 q (silu*0.125), <2048 k (silu), <4096 v (silu),
//         <4112 t_gk raw, <4128 t_g raw, else discard
__global__ __launch_bounds__(256, 2) void gemm_f16(const f16* __restrict__ A,
                                                   const f16* __restrict__ Bt,
                                                   float* __restrict__ o0,
                                                   float* __restrict__ o1,
                                                   float* __restrict__ o2,
                                                   float* __restrict__ o3,
                                                   float* __restrict__ o4,
                                                   int Ncols, int mode) {
    const int K = 2048;
    __shared__ __align__(16) f16 sA[128 * 32];
    __shared__ __align__(16) f16 sB[128 * 32];
    int tid = threadIdx.x;
    int wave = tid >> 6, lane = tid & 63;
    int quad = lane >> 4, l16 = lane & 15;
    int bm = blockIdx.x & 31;
    int bn = blockIdx.x >> 5;
    int wm = (wave >> 1) * 64, wn = (wave & 1) * 64;

    const int c0 = tid, c1 = tid + 256;
    const int ar0 = c0 >> 2, ak0 = (c0 & 3) * 8;
    const int ar1 = c1 >> 2, ak1 = (c1 & 3) * 8;
    const f16* Ab = A  + (long)(bm * 128) * K;
    const f16* Bb = Bt + (long)(bn * 128) * K;

    f32x4 acc[4][4] = {};

    for (int k0 = 0; k0 < K; k0 += 32) {
        gl_lds16(Ab + (long)ar0 * K + k0 + ak0, sA + c0 * 8);
        gl_lds16(Ab + (long)ar1 * K + k0 + ak1, sA + c1 * 8);
        gl_lds16(Bb + (long)ar0 * K + k0 + ak0, sB + c0 * 8);
        gl_lds16(Bb + (long)ar1 * K + k0 + ak1, sB + c1 * 8);
        __syncthreads();
        f16x8 af[4], bfr[4];
#pragma unroll
        for (int i = 0; i < 4; i++)
            af[i] = *(const f16x8*)(sA + (wm + i * 16 + l16) * 32 + quad * 8);
#pragma unroll
        for (int j = 0; j < 4; j++)
            bfr[j] = *(const f16x8*)(sB + (wn + j * 16 + l16) * 32 + quad * 8);
#pragma unroll
        for (int i = 0; i < 4; i++)
#pragma unroll
            for (int j = 0; j < 4; j++)
                acc[i][j] = __builtin_amdgcn_mfma_f32_16x16x32_f16(af[i], bfr[j], acc[i][j], 0, 0, 0);
        __syncthreads();
    }
#pragma unroll
    for (int i = 0; i < 4; i++)
#pragma unroll
        for (int j = 0; j < 4; j++) {
            int row0 = bm * 128 + wm + i * 16 + quad * 4;
            int col  = bn * 128 + wn + j * 16 + l16;
            if (mode == 0) {
#pragma unroll
                for (int r = 0; r < 4; r++)
                    o0[(long)(row0 + r) * Ncols + col] = acc[i][j][r];
            } else {
                float scale = 1.0f; bool dosilu = true;
                float* dst = nullptr; int cw = 0, cc = 0;
                if (col < 1024)      { dst = o0; cw = 1024; cc = col; scale = 0.125f; }
                else if (col < 2048) { dst = o1; cw = 1024; cc = col - 1024; }
                else if (col < 4096) { dst = o2; cw = 2048; cc = col - 2048; }
                else if (col < 4112) { dst = o3; cw = 16;   cc = col - 4096; dosilu = false; }
                else if (col < 4128) { dst = o4; cw = 16;   cc = col - 4112; dosilu = false; }
                if (dst) {
#pragma unroll
                    for (int r = 0; r < 4; r++) {
                        float x = acc[i][j][r];
                        if (dosilu) x = x / (1.f + __expf(-x)) * scale;
                        dst[(long)(row0 + r) * cw + cc] = x;
                    }
                }
            }
        }
}

// ---------------- GLA pass 1: per-chunk U (G precomputed) ----------------
#define ST 76
__global__ __launch_bounds__(256) void gla_pass1(const float* __restrict__ kbuf,
                                                 const float* __restrict__ vbuf,
                                                 const float* __restrict__ G,
                                                 float* __restrict__ U) {
    __shared__ float sG[64 * ST];
    __shared__ float sK[64 * ST];
    int blk = blockIdx.x;                       // (b*16+h)*32 + c
    int c = blk & 31, h = (blk >> 5) & 15, b = blk >> 9;
    int tid = threadIdx.x;
    long rowbase = (long)b * Tq + c * 64;
    const float* Gb = G + (long)blk * 4096;
#pragma unroll
    for (int i = 0; i < 4; i++) {
        int f = tid + i * 256;
        float4 v = *(const float4*)(Gb + f * 4);
        int t = f >> 4, d0 = (f & 15) * 4;
        *(float4*)&sG[t * ST + d0] = v;
    }
    __syncthreads();
#pragma unroll
    for (int i = 0; i < 16; i++) {
        int idx = tid + i * 256;
        int t = idx >> 6, d = idx & 63;
        float gl = sG[63 * ST + d];
        sK[t * ST + d] = kbuf[(rowbase + t) * 1024 + h * 64 + d] * __expf(gl - sG[t * ST + d]);
    }
    __syncthreads();
    int ty = tid >> 4, tx = tid & 15;
    float acc[4][8] = {};
    const float* vb = vbuf + rowbase * 2048 + h * 128 + tx * 8;
    for (int t = 0; t < 64; t++) {
        float kd[4];
        *(float4*)&kd[0] = *(float4*)&sK[t * ST + ty * 4];
        float4 v0 = *(const float4*)(vb + (long)t * 2048);
        float4 v1 = *(const float4*)(vb + (long)t * 2048 + 4);
        float ve[8] = {v0.x, v0.y, v0.z, v0.w, v1.x, v1.y, v1.z, v1.w};
#pragma unroll
        for (int r = 0; r < 4; r++)
#pragma unroll
            for (int e = 0; e < 8; e++) acc[r][e] += kd[r] * ve[e];
    }
    float* Ub = U + (long)blk * 8192 + (ty * 4) * 128 + tx * 8;
#pragma unroll
    for (int r = 0; r < 4; r++) {
        float4 o0 = {acc[r][0], acc[r][1], acc[r][2], acc[r][3]};
        float4 o1 = {acc[r][4], acc[r][5], acc[r][6], acc[r][7]};
        *(float4*)(Ub + r * 128)     = o0;
        *(float4*)(Ub + r * 128 + 4) = o1;
    }
}

// ---------------- GLA pass 2: scan over chunks (in-place U -> S_prev) ----------------
__global__ __launch_bounds__(256) void gla_pass2(float* __restrict__ U,
                                                 const float* __restrict__ dec) {
    int bh = blockIdx.x >> 5;
    int base = (blockIdx.x & 31) * 256 + threadIdx.x;   // 0..8191
    int d = base >> 7;
    float S = 0.f;
    long off = (long)bh * NCq * 8192 + base;
    for (int c = 0; c < NCq; c++) {
        float u = U[off + (long)c * 8192];
        float dc = dec[(bh * NCq + c) * 64 + d];
        U[off + (long)c * 8192] = S;       // state BEFORE chunk c
        S = S * dc + u;
    }
}

// ---------------- GLA pass 3: o = qg@S_prev + tril(qg kg^T)@v, fused RMS-norm+gate -> f16 --------
__global__ __launch_bounds__(256) void gla_pass3(const float* __restrict__ qbuf,
                                                 const float* __restrict__ kbuf,
                                                 const float* __restrict__ vbuf,
                                                 const float* __restrict__ G,
                                                 const float* __restrict__ t_g,
                                                 const float* __restrict__ Wg2,
                                                 const float* __restrict__ bg2,
                                                 const float* __restrict__ gnw,
                                                 const float* __restrict__ Sbuf,
                                                 f16* __restrict__ Oh) {
    __shared__ float sQ[64 * ST];
    __shared__ float sK[64 * ST];
    __shared__ float sA[64 * ST];   // G, then A
    int blk = blockIdx.x;
    int c = blk & 31, h = (blk >> 5) & 15, b = blk >> 9;
    int tid = threadIdx.x;
    long rowbase = (long)b * Tq + c * 64;
    const float* Gb = G + (long)blk * 4096;
#pragma unroll
    for (int i = 0; i < 4; i++) {
        int f = tid + i * 256;
        float4 v = *(const float4*)(Gb + f * 4);
        int t = f >> 4, d0 = (f & 15) * 4;
        *(float4*)&sA[t * ST + d0] = v;
    }
    __syncthreads();
#pragma unroll
    for (int i = 0; i < 16; i++) {
        int idx = tid + i * 256;
        int t = idx >> 6, d = idx & 63;
        float Gv = sA[t * ST + d];
        long g = (rowbase + t) * 1024 + h * 64 + d;
        sQ[t * ST + d] = qbuf[g] * __expf(Gv);
        sK[t * ST + d] = kbuf[g] * __expf(-Gv);
    }
    __syncthreads();
    int ty = tid >> 4, tx = tid & 15;
    // A = tril(sQ sK^T)
    {
        float a[4][4] = {};
        for (int d4 = 0; d4 < 16; d4++) {
            float4 qv[4], kv[4];
#pragma unroll
            for (int r = 0; r < 4; r++) qv[r] = *(const float4*)&sQ[(ty * 4 + r) * ST + d4 * 4];
#pragma unroll
            for (int cc = 0; cc < 4; cc++) kv[cc] = *(const float4*)&sK[(tx * 4 + cc) * ST + d4 * 4];
#pragma unroll
            for (int r = 0; r < 4; r++)
#pragma unroll
                for (int cc = 0; cc < 4; cc++)
                    a[r][cc] += qv[r].x * kv[cc].x + qv[r].y * kv[cc].y +
                                qv[r].z * kv[cc].z + qv[r].w * kv[cc].w;
        }
#pragma unroll
        for (int r = 0; r < 4; r++) {
            int ii = ty * 4 + r;
            float4 row;
            row.x = (tx * 4 + 0 <= ii) ? a[r][0] : 0.f;
            row.y = (tx * 4 + 1 <= ii) ? a[r][1] : 0.f;
            row.z = (tx * 4 + 2 <= ii) ? a[r][2] : 0.f;
            row.w = (tx * 4 + 3 <= ii) ? a[r][3] : 0.f;
            *(float4*)&sA[ii * ST + tx * 4] = row;
        }
    }
    __syncthreads();
    // stage gate tables into sK overlay (sK's last read was A-compute, fenced above)
    float* sWg2v = sK;          // 16*128
    float* sbg   = sK + 2048;   // 128
    {
#pragma unroll
        for (int i = 0; i < 2; i++) {
            int idx = tid * 4 + i * 1024;
            int rr = idx >> 7, ee = idx & 127;
            *(float4*)&sWg2v[idx] = *(const float4*)(Wg2 + (long)rr * 2048 + h * 128 + ee);
        }
        if (tid < 128) sbg[tid] = bg2[h * 128 + tid];
    }
    // o accumulation (reads sQ, sA, global — not the sK overlay); vectorized LDS
    float acc[4][8] = {};
    const float* Sb = Sbuf + (long)blk * 8192 + tx * 8;
    for (int d4 = 0; d4 < 16; d4++) {
        float qa[4][4];
#pragma unroll
        for (int r = 0; r < 4; r++)
            *(float4*)&qa[r][0] = *(float4*)&sQ[(ty * 4 + r) * ST + d4 * 4];
#pragma unroll
        for (int dd = 0; dd < 4; dd++) {
            int d = d4 * 4 + dd;
            float4 s0 = *(const float4*)(Sb + d * 128);
            float4 s1 = *(const float4*)(Sb + d * 128 + 4);
            float se[8] = {s0.x, s0.y, s0.z, s0.w, s1.x, s1.y, s1.z, s1.w};
#pragma unroll
            for (int r = 0; r < 4; r++) {
                float qv = qa[r][dd];
#pragma unroll
                for (int e = 0; e < 8; e++) acc[r][e] += qv * se[e];
            }
        }
    }
    const float* vb = vbuf + rowbase * 2048 + h * 128 + tx * 8;
    for (int j4 = 0; j4 <= ty; j4++) {
        float aa[4][4];
#pragma unroll
        for (int r = 0; r < 4; r++)
            *(float4*)&aa[r][0] = *(float4*)&sA[(ty * 4 + r) * ST + j4 * 4];
#pragma unroll
        for (int jj = 0; jj < 4; jj++) {
            int j = j4 * 4 + jj;
            float4 v0 = *(const float4*)(vb + (long)j * 2048);
            float4 v1 = *(const float4*)(vb + (long)j * 2048 + 4);
            float ve[8] = {v0.x, v0.y, v0.z, v0.w, v1.x, v1.y, v1.z, v1.w};
#pragma unroll
            for (int r = 0; r < 4; r++) {
                float av = aa[r][jj];
#pragma unroll
                for (int e = 0; e < 8; e++) acc[r][e] += av * ve[e];
            }
        }
    }
    __syncthreads();   // gate tables visible
    // fused epilogue: RMS-norm over DV=128 + gnw + sigmoid gate
    float4 gn0 = *(const float4*)(gnw + tx * 8);
    float4 gn1 = *(const float4*)(gnw + tx * 8 + 4);
    float4 bg0 = *(float4*)&sbg[tx * 8];
    float4 bg1 = *(float4*)&sbg[tx * 8 + 4];
#pragma unroll
    for (int half = 0; half < 2; half++) {
        float tg[2][16];
#pragma unroll
        for (int rh = 0; rh < 2; rh++) {
            const float* tgp = t_g + (rowbase + ty * 4 + half * 2 + rh) * 16;
#pragma unroll
            for (int q4 = 0; q4 < 4; q4++)
                *(float4*)&tg[rh][q4 * 4] = *(const float4*)(tgp + q4 * 4);
        }
        float g[2][8];
#pragma unroll
        for (int rh = 0; rh < 2; rh++) {
            g[rh][0] = bg0.x; g[rh][1] = bg0.y; g[rh][2] = bg0.z; g[rh][3] = bg0.w;
            g[rh][4] = bg1.x; g[rh][5] = bg1.y; g[rh][6] = bg1.z; g[rh][7] = bg1.w;
        }
#pragma unroll
        for (int rr = 0; rr < 16; rr++) {
            float4 w0 = *(float4*)&sWg2v[rr * 128 + tx * 8];
            float4 w1 = *(float4*)&sWg2v[rr * 128 + tx * 8 + 4];
#pragma unroll
            for (int rh = 0; rh < 2; rh++) {
                float t = tg[rh][rr];
                g[rh][0] += t * w0.x; g[rh][1] += t * w0.y; g[rh][2] += t * w0.z; g[rh][3] += t * w0.w;
                g[rh][4] += t * w1.x; g[rh][5] += t * w1.y; g[rh][6] += t * w1.z; g[rh][7] += t * w1.w;
            }
        }
        float gw[8] = {gn0.x, gn0.y, gn0.z, gn0.w, gn1.x, gn1.y, gn1.z, gn1.w};
#pragma unroll
        for (int rh = 0; rh < 2; rh++) {
            int r = half * 2 + rh;
            int ii = ty * 4 + r;
            float ss = 0.f;
#pragma unroll
            for (int e = 0; e < 8; e++) ss += acc[r][e] * acc[r][e];
            ss += __shfl_xor(ss, 1);
            ss += __shfl_xor(ss, 2);
            ss += __shfl_xor(ss, 4);
            ss += __shfl_xor(ss, 8);
            float scale = rsqrtf(ss * (1.f / 128.f) + 1e-5f);
            f16x8 hv;
#pragma unroll
            for (int e = 0; e < 8; e++) {
                float y = acc[r][e] * scale * gw[e] / (1.f + __expf(-g[rh][e]));
                hv[e] = (f16)y;
            }
            long off = (rowbase + ii) * 2048 + h * 128 + tx * 8;
            *(f16x8*)(Oh + off) = hv;
        }
    }
}

extern "C" void kernel_launch(void* const* d_in, const int* in_sizes, int n_in,
                              void* d_out, int out_size, void* d_ws, size_t ws_size,
                              hipStream_t stream) {
    const float* hs   = (const float*)d_in[0];
    const float* Wq   = (const float*)d_in[1];
    const float* Wk   = (const float*)d_in[2];
    const float* Wv   = (const float*)d_in[3];
    const float* Wgk1 = (const float*)d_in[4];
    const float* Wgk2 = (const float*)d_in[5];
    const float* bgk2 = (const float*)d_in[6];
    const float* Wg1  = (const float*)d_in[7];
    const float* Wg2  = (const float*)d_in[8];
    const float* bg2  = (const float*)d_in[9];
    const float* Wo   = (const float*)d_in[10];
    const float* gnw  = (const float*)d_in[11];

    char* w = (char*)d_ws;
    auto alloc = [&](size_t bytes) {
        char* p = w; w += (bytes + 255) & ~size_t(255); return (void*)p;
    };
    f16*   Xh     = (f16*)  alloc((size_t)Mq * Dq * 2);        // 16 MB (reused for O)
    f16*   WqkvT  = (f16*)  alloc((size_t)4224 * 2048 * 2);    // 17.3 MB [q|k|v|gk1|g1|pad]
    f16*   WoT    = (f16*)  alloc((size_t)2048 * 2048 * 2);    // 8 MB
    float* qb     = (float*)alloc((size_t)Mq * 1024 * 4);      // 16 MB
    float* kb     = (float*)alloc((size_t)Mq * 1024 * 4);      // 16 MB
    float* vb     = (float*)alloc((size_t)Mq * 2048 * 4);      // 32 MB
    float* t_gk   = (float*)alloc((size_t)Mq * 16 * 4);
    float* t_g    = (float*)alloc((size_t)Mq * 16 * 4);
    float* U      = (float*)alloc((size_t)NBH * NCq * 8192 * 4); // 33.5 MB (Sbuf in-place)
    float* dec    = (float*)alloc((size_t)NBH * NCq * 64 * 4);
    float* Gbuf   = (float*)alloc((size_t)NBH * NCq * 4096 * 4); // 16.8 MB

    trans_all<<<12328, 256, 0, stream>>>(Wq, Wk, Wv, Wo, Wgk1, Wg1, WqkvT, WoT);
    hs_conv<<<Mq * Dq / 2048, 256, 0, stream>>>(hs, Xh);

    // fused q|k|v|t_gk|t_g GEMM: N = 4224, 32x33 = 1056 blocks
    gemm_f16<<<32 * 33, 256, 0, stream>>>(Xh, WqkvT, qb, kb, vb, t_gk, t_g, 4224, 1);

    gk_cum<<<NBH * NCq, 256, 0, stream>>>(t_gk, Wgk2, bgk2, Gbuf, dec);
    gla_pass1<<<NBH * NCq, 256, 0, stream>>>(kb, vb, Gbuf, U);
    gla_pass2<<<NBH * NCq, 256, 0, stream>>>(U, dec);
    // pass3 writes normalized+gated output directly as f16 into Xh (X dead after qkv GEMM)
    gla_pass3<<<NBH * NCq, 256, 0, stream>>>(qb, kb, vb, Gbuf, t_g, Wg2, bg2, gnw, U, Xh);

    // out GEMM: N = 2048, 32x16 = 512 blocks
    gemm_f16<<<32 * 16, 256, 0, stream>>>(Xh, WoT, (float*)d_out, nullptr, nullptr, nullptr, nullptr, 2048, 0);
}